// Round 1
// baseline (1342.053 us; speedup 1.0000x reference)
//
#include <hip/hip_runtime.h>
#include <math.h>

#define NN 100000
#define NE 1600000
#define ET (NE + NN)   // 1,700,000 edges incl. self-loops
#define ICH 128
#define HID 64
#define NGR 64

__device__ __forceinline__ float lrelu(float x){ return x > 0.f ? x : 0.2f*x; }
__device__ __forceinline__ float eluf(float x){ return x > 0.f ? x : expm1f(x); }

__device__ __forceinline__ float wsum64(float v){
  #pragma unroll
  for (int m = 32; m >= 1; m >>= 1) v += __shfl_xor(v, m);
  return v;
}
__device__ __forceinline__ float wsum16(float v){
  v += __shfl_xor(v, 8); v += __shfl_xor(v, 4);
  v += __shfl_xor(v, 2); v += __shfl_xor(v, 1);
  return v;
}

// K1: h1 = x @ W1 (100000x128 * 128x64), plus per-head attention logits
// wave = 64 lanes = 64 output channels; each wave does 4 nodes (amortize W1 loads)
__global__ __launch_bounds__(256) void k_gemm1(const float* __restrict__ x,
    const float* __restrict__ W1, const float* __restrict__ asw,
    const float* __restrict__ adw, float* __restrict__ h1,
    float* __restrict__ as1, float* __restrict__ ad1)
{
  const int lane = threadIdx.x & 63;
  const int wid  = (blockIdx.x * 256 + threadIdx.x) >> 6;   // 0..24999
  const int n0   = __builtin_amdgcn_readfirstlane(wid * 4); // wave-uniform -> s_load path
  const float* xr = x + (size_t)n0 * ICH;
  float a0 = 0.f, a1 = 0.f, a2 = 0.f, a3 = 0.f;
  #pragma unroll 4
  for (int k = 0; k < ICH; ++k){
    const float w = W1[k * HID + lane];
    a0 = fmaf(xr[k],          w, a0);
    a1 = fmaf(xr[ICH + k],    w, a1);
    a2 = fmaf(xr[2*ICH + k],  w, a2);
    a3 = fmaf(xr[3*ICH + k],  w, a3);
  }
  const float sw = asw[lane], dw = adw[lane];  // att layout [H][16] flattens to [64]
  float acc[4] = {a0, a1, a2, a3};
  #pragma unroll
  for (int i = 0; i < 4; ++i){
    const int n = n0 + i;
    h1[(size_t)n * HID + lane] = acc[i];
    float ps = wsum16(acc[i] * sw);
    float pd = wsum16(acc[i] * dw);
    if ((lane & 15) == 0){
      as1[n * 4 + (lane >> 4)] = ps;
      ad1[n * 4 + (lane >> 4)] = pd;
    }
  }
}

// K2: per-edge exp(leaky_relu(alpha)) for 4 heads + denominator atomics.
// Max-subtraction dropped: every node has a self-loop so segment_max is finite
// and softmax is invariant to the shift (fp delta ~1e-7 << 2% tol).
__global__ __launch_bounds__(256) void k_edge1(const int* __restrict__ ei,
    const float4* __restrict__ as1, const float4* __restrict__ ad1,
    float4* __restrict__ ex1, float* __restrict__ dn1)
{
  int e = blockIdx.x * 256 + threadIdx.x;
  if (e >= ET) return;
  int s, d;
  if (e < NE){ s = ei[e]; d = ei[NE + e]; } else { s = d = e - NE; }
  float4 A = as1[s], B = ad1[d];
  float4 E;
  E.x = expf(lrelu(A.x + B.x));
  E.y = expf(lrelu(A.y + B.y));
  E.z = expf(lrelu(A.z + B.z));
  E.w = expf(lrelu(A.w + B.w));
  ex1[e] = E;
  atomicAdd(&dn1[4*d+0], E.x);
  atomicAdd(&dn1[4*d+1], E.y);
  atomicAdd(&dn1[4*d+2], E.z);
  atomicAdd(&dn1[4*d+3], E.w);
}

// K3: message pass conv1: out1[d][c] += h1[s][c] * w_e   (1 thread per edge-channel)
__global__ __launch_bounds__(256) void k_msg1(const int* __restrict__ ei,
    const float* __restrict__ h1, const float* __restrict__ ex1,
    const float* __restrict__ dn1, float* __restrict__ out1)
{
  const int t = blockIdx.x * 256 + threadIdx.x;
  const int e = t >> 6;
  if (e >= ET) return;
  const int c = t & 63;
  int s, d;
  if (e < NE){ s = ei[e]; d = ei[NE + e]; } else { s = d = e - NE; }
  const int h = c >> 4;
  const float w = ex1[4*e + h] / (dn1[4*d + h] + 1e-16f);
  atomicAdd(&out1[(size_t)d * HID + c], h1[(size_t)s * HID + c] * w);
}

// K4a: h = elu(out1 + b1), in place
__global__ __launch_bounds__(256) void k_elu1(float* __restrict__ hb,
                                              const float* __restrict__ b1)
{
  int i = blockIdx.x * 256 + threadIdx.x;   // NN*64 = 6.4M threads exact
  float v = hb[i] + b1[i & 63];
  hb[i] = eluf(v);
}

// K4b: h2 = h @ W2 (64x64) + scalar-head attention logits
__global__ __launch_bounds__(256) void k_gemm2(const float* __restrict__ h,
    const float* __restrict__ W2, const float* __restrict__ asw,
    const float* __restrict__ adw, float* __restrict__ h2,
    float* __restrict__ as2, float* __restrict__ ad2)
{
  const int lane = threadIdx.x & 63;
  const int wid  = (blockIdx.x * 256 + threadIdx.x) >> 6;
  const int n0   = __builtin_amdgcn_readfirstlane(wid * 4);
  const float* hr = h + (size_t)n0 * HID;
  float a0 = 0.f, a1 = 0.f, a2 = 0.f, a3 = 0.f;
  #pragma unroll 4
  for (int k = 0; k < HID; ++k){
    const float w = W2[k * HID + lane];
    a0 = fmaf(hr[k],          w, a0);
    a1 = fmaf(hr[HID + k],    w, a1);
    a2 = fmaf(hr[2*HID + k],  w, a2);
    a3 = fmaf(hr[3*HID + k],  w, a3);
  }
  const float sw = asw[lane], dw = adw[lane];
  float acc[4] = {a0, a1, a2, a3};
  #pragma unroll
  for (int i = 0; i < 4; ++i){
    const int n = n0 + i;
    h2[(size_t)n * HID + lane] = acc[i];
    float ps = wsum64(acc[i] * sw);
    float pd = wsum64(acc[i] * dw);
    if (lane == 0){ as2[n] = ps; ad2[n] = pd; }
  }
}

// K5: conv2 per-edge exp + denominator
__global__ __launch_bounds__(256) void k_edge2(const int* __restrict__ ei,
    const float* __restrict__ as2, const float* __restrict__ ad2,
    float* __restrict__ ex2, float* __restrict__ dn2)
{
  int e = blockIdx.x * 256 + threadIdx.x;
  if (e >= ET) return;
  int s, d;
  if (e < NE){ s = ei[e]; d = ei[NE + e]; } else { s = d = e - NE; }
  float v = expf(lrelu(as2[s] + ad2[d]));
  ex2[e] = v;
  atomicAdd(&dn2[d], v);
}

// K6: message pass conv2
__global__ __launch_bounds__(256) void k_msg2(const int* __restrict__ ei,
    const float* __restrict__ h2, const float* __restrict__ ex2,
    const float* __restrict__ dn2, float* __restrict__ out2)
{
  const int t = blockIdx.x * 256 + threadIdx.x;
  const int e = t >> 6;
  if (e >= ET) return;
  const int c = t & 63;
  int s, d;
  if (e < NE){ s = ei[e]; d = ei[NE + e]; } else { s = d = e - NE; }
  const float w = ex2[e] / (dn2[d] + 1e-16f);
  atomicAdd(&out2[(size_t)d * HID + c], h2[(size_t)s * HID + c] * w);
}

// K7: residual + LayerNorm + elu + pool logits; hf written in place of out2
__global__ __launch_bounds__(256) void k_post(float* __restrict__ o2,
    const float* __restrict__ hres, const float* __restrict__ b2,
    const float* __restrict__ lng, const float* __restrict__ lnb,
    const float* __restrict__ wpool, const float* __restrict__ bpool,
    float* __restrict__ es)
{
  const int lane = threadIdx.x & 63;
  const int n = (blockIdx.x * 256 + threadIdx.x) >> 6;
  const size_t idx = (size_t)n * HID + lane;
  float t = o2[idx] + b2[lane] + hres[idx];
  float mu  = wsum64(t) * (1.f/64.f);
  float dv  = t - mu;
  float var = wsum64(dv * dv) * (1.f/64.f);
  float hf = dv * (1.f / sqrtf(var + 1e-5f)) * lng[lane] + lnb[lane];
  hf = eluf(hf);
  o2[idx] = hf;
  float s = wsum64(hf * wpool[lane]) + bpool[0];
  if (lane == 0) es[n] = expf(s);  // global softmax: max-shift dropped (|s|<~6)
}

// K8: S = sum(es)
__global__ __launch_bounds__(256) void k_sumes(const float* __restrict__ es,
                                               float* __restrict__ S)
{
  float v = 0.f;
  for (int i = blockIdx.x * 256 + threadIdx.x; i < NN; i += gridDim.x * 256)
    v += es[i];
  v = wsum64(v);
  __shared__ float red[4];
  if ((threadIdx.x & 63) == 0) red[threadIdx.x >> 6] = v;
  __syncthreads();
  if (threadIdx.x == 0) atomicAdd(S, red[0] + red[1] + red[2] + red[3]);
}

// K9: pooled[g][c] = sum_{n in g} hf[n][c] * es[n]/S ; batch is sorted so each
// wave accumulates a 64-node run in registers and flushes per graph change.
__global__ __launch_bounds__(256) void k_pool(const float* __restrict__ hf,
    const float* __restrict__ es, const int* __restrict__ batch,
    const float* __restrict__ S, float* __restrict__ pooled)
{
  const int lane = threadIdx.x & 63;
  const int wseg = blockIdx.x * 4 + (threadIdx.x >> 6);
  const int base = wseg * 64;
  if (base >= NN) return;
  const float invS = 1.f / S[0];
  int end = base + 64; if (end > NN) end = NN;
  float acc = 0.f;
  int gprev = batch[base];
  for (int n = base; n < end; ++n){
    int g = batch[n];
    if (g != gprev){
      atomicAdd(&pooled[gprev * HID + lane], acc);
      acc = 0.f; gprev = g;
    }
    acc = fmaf(hf[(size_t)n * HID + lane], es[n] * invS, acc);
  }
  atomicAdd(&pooled[gprev * HID + lane], acc);
}

// K10: z = elu(pooled@w_fc1+b_fc1); out = z@w_fc2+b_fc2  (64 graphs)
__global__ __launch_bounds__(64) void k_head(const float* __restrict__ pooled,
    const float* __restrict__ wfc1, const float* __restrict__ bfc1,
    const float* __restrict__ wfc2, const float* __restrict__ bfc2,
    float* __restrict__ out)
{
  const int g = blockIdx.x, j = threadIdx.x;
  const float* pr = pooled + g * HID;
  float acc = bfc1[j];
  #pragma unroll 4
  for (int k = 0; k < HID; ++k) acc = fmaf(pr[k], wfc1[k * HID + j], acc);
  float z = eluf(acc);
  float r = wsum64(z * wfc2[j]);
  if (j == 0) out[g] = r + bfc2[0];
}

extern "C" void kernel_launch(void* const* d_in, const int* in_sizes, int n_in,
                              void* d_out, int out_size, void* d_ws, size_t ws_size,
                              hipStream_t stream)
{
  const float* x     = (const float*)d_in[0];
  const int*   ei    = (const int*)d_in[1];
  const int*   batch = (const int*)d_in[2];
  const float* W1    = (const float*)d_in[4];
  const float* asw1  = (const float*)d_in[5];
  const float* adw1  = (const float*)d_in[6];
  const float* b1    = (const float*)d_in[7];
  const float* W2    = (const float*)d_in[8];
  const float* asw2  = (const float*)d_in[9];
  const float* adw2  = (const float*)d_in[10];
  const float* b2    = (const float*)d_in[11];
  const float* lng   = (const float*)d_in[12];
  const float* lnb   = (const float*)d_in[13];
  const float* wpool = (const float*)d_in[14];
  const float* bpool = (const float*)d_in[15];
  const float* wfc1  = (const float*)d_in[16];
  const float* bfc1  = (const float*)d_in[17];
  const float* wfc2  = (const float*)d_in[18];
  const float* bfc2  = (const float*)d_in[19];

  float* ws = (float*)d_ws;
  float* h1     = ws;              // NN*64  (reused as h2 after conv1)
  float* hb     = ws + 6400000;    // out1 accum -> h (post-elu, residual)
  float* o2     = ws + 12800000;   // out2 accum -> hf (in place)
  float* ex1    = ws + 19200000;   // ET*4   (first ET floats reused as ex2)
  float* as1    = ws + 26000000;   // NN*4
  float* ad1    = ws + 26400000;   // NN*4
  float* dn1    = ws + 26800000;   // NN*4
  float* as2    = ws + 27200000;   // NN
  float* ad2    = ws + 27300000;   // NN
  float* dn2    = ws + 27400000;   // NN
  float* es     = ws + 27500000;   // NN
  float* pooled = ws + 27600000;   // 64*64
  float* Ssum   = ws + 27604096;   // 1
  // total ~27.61M floats = 110.5 MB of d_ws

  // accumulators must be re-zeroed every launch (harness poisons ws once)
  hipMemsetAsync(hb,   0, (size_t)6400000 * 4, stream);
  hipMemsetAsync(o2,   0, (size_t)6400000 * 4, stream);
  hipMemsetAsync(dn1,  0, (size_t)400000 * 4, stream);
  hipMemsetAsync(dn2,  0, (size_t)100000 * 4, stream);
  hipMemsetAsync(pooled, 0, (size_t)NGR * 64 * 4, stream);
  hipMemsetAsync(Ssum, 0, 4, stream);

  k_gemm1<<<6250, 256, 0, stream>>>(x, W1, asw1, adw1, h1, as1, ad1);
  k_edge1<<<(ET + 255) / 256, 256, 0, stream>>>(ei, (const float4*)as1,
                                                (const float4*)ad1, (float4*)ex1, dn1);
  k_msg1<<<ET / 4, 256, 0, stream>>>(ei, h1, ex1, dn1, hb);
  k_elu1<<<25000, 256, 0, stream>>>(hb, b1);
  k_gemm2<<<6250, 256, 0, stream>>>(hb, W2, asw2, adw2, h1, as2, ad2);
  k_edge2<<<(ET + 255) / 256, 256, 0, stream>>>(ei, as2, ad2, ex1, dn2);
  k_msg2<<<ET / 4, 256, 0, stream>>>(ei, h1, ex1, dn2, o2);
  k_post<<<25000, 256, 0, stream>>>(o2, hb, b2, lng, lnb, wpool, bpool, es);
  k_sumes<<<128, 256, 0, stream>>>(es, Ssum);
  k_pool<<<391, 256, 0, stream>>>(o2, es, batch, Ssum, pooled);
  k_head<<<64, 64, 0, stream>>>(pooled, wfc1, bfc1, wfc2, bfc2, (float*)d_out);
}

// Round 2
// 594.835 us; speedup vs baseline: 2.2562x; 2.2562x over previous
//
#include <hip/hip_runtime.h>
#include <math.h>

#define NN 100000
#define NE 1600000
#define ET (NE + NN)   // 1,700,000 edges incl. self-loops
#define ICH 128
#define HID 64
#define NGR 64
#define NB_SCAN 391    // ceil(100000/256)

__device__ __forceinline__ float lrelu(float x){ return x > 0.f ? x : 0.2f*x; }
__device__ __forceinline__ float eluf(float x){ return x > 0.f ? x : expm1f(x); }

__device__ __forceinline__ float wsum64(float v){
  #pragma unroll
  for (int m = 32; m >= 1; m >>= 1) v += __shfl_xor(v, m);
  return v;
}
__device__ __forceinline__ float wsum16(float v){
  v += __shfl_xor(v, 8); v += __shfl_xor(v, 4);
  v += __shfl_xor(v, 2); v += __shfl_xor(v, 1);
  return v;
}
__device__ __forceinline__ int wscan_incl(int v){
  const int lane = threadIdx.x & 63;
  #pragma unroll
  for (int d = 1; d < 64; d <<= 1){
    int t = __shfl_up(v, d);
    if (lane >= d) v += t;
  }
  return v;
}

// ---------------- CSR build ----------------
__global__ __launch_bounds__(256) void k_deg(const int* __restrict__ ei,
                                             int* __restrict__ deg)
{
  int e = blockIdx.x * 256 + threadIdx.x;
  if (e >= ET) return;
  int d = (e < NE) ? ei[NE + e] : (e - NE);
  atomicAdd(&deg[d], 1);
}

// block-local exclusive scan of deg -> rowptr, block sums -> bsum
__global__ __launch_bounds__(256) void k_scanA(const int* __restrict__ deg,
    int* __restrict__ rowptr, int* __restrict__ bsum)
{
  int i = blockIdx.x * 256 + threadIdx.x;
  int v = (i < NN) ? deg[i] : 0;
  int incl = wscan_incl(v);
  __shared__ int wsums[4];
  int w = threadIdx.x >> 6, lane = threadIdx.x & 63;
  if (lane == 63) wsums[w] = incl;
  __syncthreads();
  int off = 0;
  for (int k = 0; k < w; ++k) off += wsums[k];
  if (i < NN) rowptr[i] = incl - v + off;
  if (threadIdx.x == 255) bsum[blockIdx.x] = off + incl;
}

// single block: exclusive scan of the NB_SCAN block sums
__global__ __launch_bounds__(512) void k_scanB(const int* __restrict__ bsum,
                                               int* __restrict__ boff)
{
  int i = threadIdx.x;
  int v = (i < NB_SCAN) ? bsum[i] : 0;
  int incl = wscan_incl(v);
  __shared__ int wsums[8];
  int w = threadIdx.x >> 6, lane = threadIdx.x & 63;
  if (lane == 63) wsums[w] = incl;
  __syncthreads();
  int off = 0;
  for (int k = 0; k < w; ++k) off += wsums[k];
  if (i < NB_SCAN) boff[i] = incl - v + off;
}

__global__ __launch_bounds__(256) void k_scanC(int* __restrict__ rowptr,
    const int* __restrict__ boff, int* __restrict__ cursor)
{
  int i = blockIdx.x * 256 + threadIdx.x;
  if (i < NN){
    int val = rowptr[i] + boff[blockIdx.x];
    rowptr[i] = val;
    cursor[i] = val;
  }
  if (i == 0) rowptr[NN] = ET;
}

__global__ __launch_bounds__(256) void k_scatter(const int* __restrict__ ei,
    int* __restrict__ cursor, int* __restrict__ csr_src)
{
  int e = blockIdx.x * 256 + threadIdx.x;
  if (e >= ET) return;
  int s, d;
  if (e < NE){ s = ei[e]; d = ei[NE + e]; } else { s = d = e - NE; }
  int pos = atomicAdd(&cursor[d], 1);
  csr_src[pos] = s;
}

// ---------------- dense node kernels ----------------
// K1: h1 = x @ W1 (100000x128 * 128x64) + per-head attention logits
__global__ __launch_bounds__(256) void k_gemm1(const float* __restrict__ x,
    const float* __restrict__ W1, const float* __restrict__ asw,
    const float* __restrict__ adw, float* __restrict__ h1,
    float* __restrict__ as1, float* __restrict__ ad1)
{
  const int lane = threadIdx.x & 63;
  const int wid  = (blockIdx.x * 256 + threadIdx.x) >> 6;   // 0..24999
  const int n0   = __builtin_amdgcn_readfirstlane(wid * 4); // wave-uniform -> s_load path
  const float* xr = x + (size_t)n0 * ICH;
  float a0 = 0.f, a1 = 0.f, a2 = 0.f, a3 = 0.f;
  #pragma unroll 4
  for (int k = 0; k < ICH; ++k){
    const float w = W1[k * HID + lane];
    a0 = fmaf(xr[k],          w, a0);
    a1 = fmaf(xr[ICH + k],    w, a1);
    a2 = fmaf(xr[2*ICH + k],  w, a2);
    a3 = fmaf(xr[3*ICH + k],  w, a3);
  }
  const float sw = asw[lane], dw = adw[lane];  // att layout [H][16] flattens to [64]
  float acc[4] = {a0, a1, a2, a3};
  #pragma unroll
  for (int i = 0; i < 4; ++i){
    const int n = n0 + i;
    h1[(size_t)n * HID + lane] = acc[i];
    float ps = wsum16(acc[i] * sw);
    float pd = wsum16(acc[i] * dw);
    if ((lane & 15) == 0){
      as1[n * 4 + (lane >> 4)] = ps;
      ad1[n * 4 + (lane >> 4)] = pd;
    }
  }
}

// conv1 node-centric: one wave per dst node; softmax denom in regs, gather-
// accumulate messages, fused elu(+b1) epilogue. No atomics anywhere.
// Max-subtraction dropped: self-loop guarantees finite max; softmax invariant.
__global__ __launch_bounds__(256) void k_conv1(const int* __restrict__ rowptr,
    const int* __restrict__ csr_src, const float4* __restrict__ as1,
    const float4* __restrict__ ad1, const float* __restrict__ h1,
    const float* __restrict__ b1, float* __restrict__ hb)
{
  const int lane = threadIdx.x & 63;
  const int n = (blockIdx.x * 256 + threadIdx.x) >> 6;
  const int row0 = rowptr[n], row1 = rowptr[n + 1];
  const float4 adv = ad1[n];
  // pass 1: denominators (4 heads)
  float4 dns = {0.f, 0.f, 0.f, 0.f};
  for (int base = row0; base < row1; base += 64){
    int idx = base + lane;
    if (idx < row1){
      int s = csr_src[idx];
      float4 a = as1[s];
      dns.x += expf(lrelu(a.x + adv.x));
      dns.y += expf(lrelu(a.y + adv.y));
      dns.z += expf(lrelu(a.z + adv.z));
      dns.w += expf(lrelu(a.w + adv.w));
    }
  }
  dns.x = wsum64(dns.x); dns.y = wsum64(dns.y);
  dns.z = wsum64(dns.z); dns.w = wsum64(dns.w);
  const int h = lane >> 4;
  float invh = 1.f / ((h == 0 ? dns.x : h == 1 ? dns.y : h == 2 ? dns.z : dns.w) + 1e-16f);
  // pass 2: gather-accumulate
  float acc = 0.f;
  for (int base = row0; base < row1; base += 64){
    int cnt = row1 - base; if (cnt > 64) cnt = 64;
    int idx = base + lane;
    int s = 0; float4 ex = {0.f, 0.f, 0.f, 0.f};
    if (idx < row1){
      s = csr_src[idx];
      float4 a = as1[s];
      ex.x = expf(lrelu(a.x + adv.x));
      ex.y = expf(lrelu(a.y + adv.y));
      ex.z = expf(lrelu(a.z + adv.z));
      ex.w = expf(lrelu(a.w + adv.w));
    }
    for (int j = 0; j < cnt; ++j){
      int sj = __shfl(s, j);
      float e0 = __shfl(ex.x, j), e1 = __shfl(ex.y, j);
      float e2 = __shfl(ex.z, j), e3 = __shfl(ex.w, j);
      float eh = h == 0 ? e0 : h == 1 ? e1 : h == 2 ? e2 : e3;
      acc = fmaf(h1[(size_t)sj * HID + lane], eh * invh, acc);
    }
  }
  hb[(size_t)n * HID + lane] = eluf(acc + b1[lane]);
}

// K4b: h2 = h @ W2 (64x64) + scalar-head attention logits
__global__ __launch_bounds__(256) void k_gemm2(const float* __restrict__ h,
    const float* __restrict__ W2, const float* __restrict__ asw,
    const float* __restrict__ adw, float* __restrict__ h2,
    float* __restrict__ as2, float* __restrict__ ad2)
{
  const int lane = threadIdx.x & 63;
  const int wid  = (blockIdx.x * 256 + threadIdx.x) >> 6;
  const int n0   = __builtin_amdgcn_readfirstlane(wid * 4);
  const float* hr = h + (size_t)n0 * HID;
  float a0 = 0.f, a1 = 0.f, a2 = 0.f, a3 = 0.f;
  #pragma unroll 4
  for (int k = 0; k < HID; ++k){
    const float w = W2[k * HID + lane];
    a0 = fmaf(hr[k],          w, a0);
    a1 = fmaf(hr[HID + k],    w, a1);
    a2 = fmaf(hr[2*HID + k],  w, a2);
    a3 = fmaf(hr[3*HID + k],  w, a3);
  }
  const float sw = asw[lane], dw = adw[lane];
  float acc[4] = {a0, a1, a2, a3};
  #pragma unroll
  for (int i = 0; i < 4; ++i){
    const int n = n0 + i;
    h2[(size_t)n * HID + lane] = acc[i];
    float ps = wsum64(acc[i] * sw);
    float pd = wsum64(acc[i] * dw);
    if (lane == 0){ as2[n] = ps; ad2[n] = pd; }
  }
}

// conv2 node-centric + fused residual + LayerNorm + elu + pool logit.
__global__ __launch_bounds__(256) void k_conv2(const int* __restrict__ rowptr,
    const int* __restrict__ csr_src, const float* __restrict__ as2,
    const float* __restrict__ ad2, const float* __restrict__ h2,
    const float* __restrict__ b2, const float* __restrict__ hres,
    const float* __restrict__ lng, const float* __restrict__ lnb,
    const float* __restrict__ wpool, const float* __restrict__ bpool,
    float* __restrict__ hf, float* __restrict__ es)
{
  const int lane = threadIdx.x & 63;
  const int n = (blockIdx.x * 256 + threadIdx.x) >> 6;
  const int row0 = rowptr[n], row1 = rowptr[n + 1];
  const float adn = ad2[n];
  float dn = 0.f;
  for (int base = row0; base < row1; base += 64){
    int idx = base + lane;
    if (idx < row1){
      int s = csr_src[idx];
      dn += expf(lrelu(as2[s] + adn));
    }
  }
  dn = wsum64(dn);
  const float inv = 1.f / (dn + 1e-16f);
  float acc = 0.f;
  for (int base = row0; base < row1; base += 64){
    int cnt = row1 - base; if (cnt > 64) cnt = 64;
    int idx = base + lane;
    int s = 0; float ex = 0.f;
    if (idx < row1){
      s = csr_src[idx];
      ex = expf(lrelu(as2[s] + adn));
    }
    for (int j = 0; j < cnt; ++j){
      int sj = __shfl(s, j);
      float w = __shfl(ex, j) * inv;
      acc = fmaf(h2[(size_t)sj * HID + lane], w, acc);
    }
  }
  // fused k_post: residual + LN + elu + pool logit
  const size_t idxn = (size_t)n * HID + lane;
  float t = acc + b2[lane] + hres[idxn];
  float mu  = wsum64(t) * (1.f / 64.f);
  float dv  = t - mu;
  float var = wsum64(dv * dv) * (1.f / 64.f);
  float hv = dv * (1.f / sqrtf(var + 1e-5f)) * lng[lane] + lnb[lane];
  hv = eluf(hv);
  hf[idxn] = hv;
  float sl = wsum64(hv * wpool[lane]) + bpool[0];
  if (lane == 0) es[n] = expf(sl);   // global softmax: max-shift dropped (|logit| small)
}

// S = sum(es)
__global__ __launch_bounds__(256) void k_sumes(const float* __restrict__ es,
                                               float* __restrict__ S)
{
  float v = 0.f;
  for (int i = blockIdx.x * 256 + threadIdx.x; i < NN; i += gridDim.x * 256)
    v += es[i];
  v = wsum64(v);
  __shared__ float red[4];
  if ((threadIdx.x & 63) == 0) red[threadIdx.x >> 6] = v;
  __syncthreads();
  if (threadIdx.x == 0) atomicAdd(S, red[0] + red[1] + red[2] + red[3]);
}

// pooled[g][c] = sum_{n in g} hf[n][c] * es[n]/S
__global__ __launch_bounds__(256) void k_pool(const float* __restrict__ hf,
    const float* __restrict__ es, const int* __restrict__ batch,
    const float* __restrict__ S, float* __restrict__ pooled)
{
  const int lane = threadIdx.x & 63;
  const int wseg = blockIdx.x * 4 + (threadIdx.x >> 6);
  const int base = wseg * 64;
  if (base >= NN) return;
  const float invS = 1.f / S[0];
  int end = base + 64; if (end > NN) end = NN;
  float acc = 0.f;
  int gprev = batch[base];
  for (int n = base; n < end; ++n){
    int g = batch[n];
    if (g != gprev){
      atomicAdd(&pooled[gprev * HID + lane], acc);
      acc = 0.f; gprev = g;
    }
    acc = fmaf(hf[(size_t)n * HID + lane], es[n] * invS, acc);
  }
  atomicAdd(&pooled[gprev * HID + lane], acc);
}

// z = elu(pooled@w_fc1+b_fc1); out = z@w_fc2+b_fc2
__global__ __launch_bounds__(64) void k_head(const float* __restrict__ pooled,
    const float* __restrict__ wfc1, const float* __restrict__ bfc1,
    const float* __restrict__ wfc2, const float* __restrict__ bfc2,
    float* __restrict__ out)
{
  const int g = blockIdx.x, j = threadIdx.x;
  const float* pr = pooled + g * HID;
  float acc = bfc1[j];
  #pragma unroll 4
  for (int k = 0; k < HID; ++k) acc = fmaf(pr[k], wfc1[k * HID + j], acc);
  float z = eluf(acc);
  float r = wsum64(z * wfc2[j]);
  if (j == 0) out[g] = r + bfc2[0];
}

extern "C" void kernel_launch(void* const* d_in, const int* in_sizes, int n_in,
                              void* d_out, int out_size, void* d_ws, size_t ws_size,
                              hipStream_t stream)
{
  const float* x     = (const float*)d_in[0];
  const int*   ei    = (const int*)d_in[1];
  const int*   batch = (const int*)d_in[2];
  const float* W1    = (const float*)d_in[4];
  const float* asw1  = (const float*)d_in[5];
  const float* adw1  = (const float*)d_in[6];
  const float* b1    = (const float*)d_in[7];
  const float* W2    = (const float*)d_in[8];
  const float* asw2  = (const float*)d_in[9];
  const float* adw2  = (const float*)d_in[10];
  const float* b2    = (const float*)d_in[11];
  const float* lng   = (const float*)d_in[12];
  const float* lnb   = (const float*)d_in[13];
  const float* wpool = (const float*)d_in[14];
  const float* bpool = (const float*)d_in[15];
  const float* wfc1  = (const float*)d_in[16];
  const float* bfc1  = (const float*)d_in[17];
  const float* wfc2  = (const float*)d_in[18];
  const float* bfc2  = (const float*)d_in[19];

  float* ws = (float*)d_ws;
  float* h1     = ws;               // NN*64 (reused as h2 after conv1)
  float* hb     = ws + 6400000;     // conv1 output post-elu (residual input)
  float* hf     = ws + 12800000;    // final node features
  float* as1    = ws + 19200000;    // NN*4
  float* ad1    = ws + 19600000;    // NN*4
  float* as2    = ws + 20000000;    // NN
  float* ad2    = ws + 20100000;    // NN
  float* es     = ws + 20200000;    // NN
  float* pooled = ws + 20300000;    // 64*64
  float* Ssum   = ws + 20304100;    // 1
  int* iw       = (int*)(ws + 20304104);
  int* rowptr   = iw;               // NN+1
  int* cursor   = iw + 100004;      // NN
  int* deg      = iw + 200004;      // NN
  int* bsum     = iw + 300004;      // 512
  int* boff     = iw + 300516;      // 512
  int* csr_src  = iw + 301028;      // ET
  // total ~22.3M words = 89.2 MB of d_ws

  hipMemsetAsync(deg, 0, (size_t)NN * 4, stream);
  hipMemsetAsync(pooled, 0, (size_t)NGR * 64 * 4, stream);
  hipMemsetAsync(Ssum, 0, 4, stream);

  // CSR build (deterministic up to within-node edge order; fp noise << tol)
  k_deg    <<<(ET + 255) / 256, 256, 0, stream>>>(ei, deg);
  k_scanA  <<<NB_SCAN, 256, 0, stream>>>(deg, rowptr, bsum);
  k_scanB  <<<1, 512, 0, stream>>>(bsum, boff);
  k_scanC  <<<NB_SCAN, 256, 0, stream>>>(rowptr, boff, cursor);
  k_scatter<<<(ET + 255) / 256, 256, 0, stream>>>(ei, cursor, csr_src);

  k_gemm1<<<6250, 256, 0, stream>>>(x, W1, asw1, adw1, h1, as1, ad1);
  k_conv1<<<25000, 256, 0, stream>>>(rowptr, csr_src, (const float4*)as1,
                                     (const float4*)ad1, h1, b1, hb);
  k_gemm2<<<6250, 256, 0, stream>>>(hb, W2, asw2, adw2, h1, as2, ad2);
  k_conv2<<<25000, 256, 0, stream>>>(rowptr, csr_src, as2, ad2, h1, b2, hb,
                                     lng, lnb, wpool, bpool, hf, es);
  k_sumes<<<128, 256, 0, stream>>>(es, Ssum);
  k_pool <<<391, 256, 0, stream>>>(hf, es, batch, Ssum, pooled);
  k_head <<<64, 64, 0, stream>>>(pooled, wfc1, bfc1, wfc2, bfc2, (float*)d_out);
}

// Round 3
// 475.093 us; speedup vs baseline: 2.8248x; 1.2520x over previous
//
#include <hip/hip_runtime.h>
#include <math.h>

#define NN 100000
#define NE 1600000
#define ET (NE + NN)   // 1,700,000 edges incl. self-loops
#define ICH 128
#define HID 64
#define NGR 64
#define NB_SCAN 391    // ceil(100000/256)

__device__ __forceinline__ float lrelu(float x){ return x > 0.f ? x : 0.2f*x; }
__device__ __forceinline__ float eluf(float x){ return x > 0.f ? x : expm1f(x); }

__device__ __forceinline__ float wsum64(float v){
  #pragma unroll
  for (int m = 32; m >= 1; m >>= 1) v += __shfl_xor(v, m);
  return v;
}
__device__ __forceinline__ float wsum16(float v){
  v += __shfl_xor(v, 8); v += __shfl_xor(v, 4);
  v += __shfl_xor(v, 2); v += __shfl_xor(v, 1);
  return v;
}
__device__ __forceinline__ int wscan_incl(int v){
  const int lane = threadIdx.x & 63;
  #pragma unroll
  for (int d = 1; d < 64; d <<= 1){
    int t = __shfl_up(v, d);
    if (lane >= d) v += t;
  }
  return v;
}

// ---------------- CSR build ----------------
__global__ __launch_bounds__(256) void k_deg(const int* __restrict__ ei,
                                             int* __restrict__ deg)
{
  int e = blockIdx.x * 256 + threadIdx.x;
  if (e >= ET) return;
  int d = (e < NE) ? ei[NE + e] : (e - NE);
  atomicAdd(&deg[d], 1);
}

__global__ __launch_bounds__(256) void k_scanA(const int* __restrict__ deg,
    int* __restrict__ rowptr, int* __restrict__ bsum)
{
  int i = blockIdx.x * 256 + threadIdx.x;
  int v = (i < NN) ? deg[i] : 0;
  int incl = wscan_incl(v);
  __shared__ int wsums[4];
  int w = threadIdx.x >> 6, lane = threadIdx.x & 63;
  if (lane == 63) wsums[w] = incl;
  __syncthreads();
  int off = 0;
  for (int k = 0; k < w; ++k) off += wsums[k];
  if (i < NN) rowptr[i] = incl - v + off;
  if (threadIdx.x == 255) bsum[blockIdx.x] = off + incl;
}

__global__ __launch_bounds__(512) void k_scanB(const int* __restrict__ bsum,
                                               int* __restrict__ boff)
{
  int i = threadIdx.x;
  int v = (i < NB_SCAN) ? bsum[i] : 0;
  int incl = wscan_incl(v);
  __shared__ int wsums[8];
  int w = threadIdx.x >> 6, lane = threadIdx.x & 63;
  if (lane == 63) wsums[w] = incl;
  __syncthreads();
  int off = 0;
  for (int k = 0; k < w; ++k) off += wsums[k];
  if (i < NB_SCAN) boff[i] = incl - v + off;
}

__global__ __launch_bounds__(256) void k_scanC(int* __restrict__ rowptr,
    const int* __restrict__ boff, int* __restrict__ cursor)
{
  int i = blockIdx.x * 256 + threadIdx.x;
  if (i < NN){
    int val = rowptr[i] + boff[blockIdx.x];
    rowptr[i] = val;
    cursor[i] = val;
  }
  if (i == 0) rowptr[NN] = ET;
}

__global__ __launch_bounds__(256) void k_scatter(const int* __restrict__ ei,
    int* __restrict__ cursor, int* __restrict__ csr_src, int* __restrict__ csr_dst)
{
  int e = blockIdx.x * 256 + threadIdx.x;
  if (e >= ET) return;
  int s, d;
  if (e < NE){ s = ei[e]; d = ei[NE + e]; } else { s = d = e - NE; }
  int pos = atomicAdd(&cursor[d], 1);
  csr_src[pos] = s;
  csr_dst[pos] = d;
}

// ---------------- dense node kernels ----------------
// h1 = x @ W1 (100000x128 * 128x64) + per-head attention logits
__global__ __launch_bounds__(256) void k_gemm1(const float* __restrict__ x,
    const float* __restrict__ W1, const float* __restrict__ asw,
    const float* __restrict__ adw, float* __restrict__ h1,
    float* __restrict__ as1, float* __restrict__ ad1)
{
  const int lane = threadIdx.x & 63;
  const int wid  = (blockIdx.x * 256 + threadIdx.x) >> 6;   // 0..24999
  const int n0   = __builtin_amdgcn_readfirstlane(wid * 4);
  const float* xr = x + (size_t)n0 * ICH;
  float a0 = 0.f, a1 = 0.f, a2 = 0.f, a3 = 0.f;
  #pragma unroll 4
  for (int k = 0; k < ICH; ++k){
    const float w = W1[k * HID + lane];
    a0 = fmaf(xr[k],          w, a0);
    a1 = fmaf(xr[ICH + k],    w, a1);
    a2 = fmaf(xr[2*ICH + k],  w, a2);
    a3 = fmaf(xr[3*ICH + k],  w, a3);
  }
  const float sw = asw[lane], dw = adw[lane];  // att layout [H][16] flattens to [64]
  float acc[4] = {a0, a1, a2, a3};
  #pragma unroll
  for (int i = 0; i < 4; ++i){
    const int n = n0 + i;
    h1[(size_t)n * HID + lane] = acc[i];
    float ps = wsum16(acc[i] * sw);
    float pd = wsum16(acc[i] * dw);
    if ((lane & 15) == 0){
      as1[n * 4 + (lane >> 4)] = ps;
      ad1[n * 4 + (lane >> 4)] = pd;
    }
  }
}

// per-edge softmax numerators in CSR order, 4 heads (computed ONCE).
// Max-subtraction dropped: self-loop guarantees finite max; softmax invariant.
__global__ __launch_bounds__(256) void k_att1(const int* __restrict__ csr_src,
    const int* __restrict__ csr_dst, const float4* __restrict__ as1,
    const float4* __restrict__ ad1, float4* __restrict__ ex1)
{
  int i = blockIdx.x * 256 + threadIdx.x;
  if (i >= ET) return;
  float4 a = as1[csr_src[i]], b = ad1[csr_dst[i]];
  float4 E;
  E.x = expf(lrelu(a.x + b.x));
  E.y = expf(lrelu(a.y + b.y));
  E.z = expf(lrelu(a.z + b.z));
  E.w = expf(lrelu(a.w + b.w));
  ex1[i] = E;
}

// conv1: single pass per node. Normalization factored out of the sum:
// out = (Σ ex_e·h1[s]) / (Σ ex_e). Every lane sums its head's ex over ALL
// edges -> den complete per-lane, no reduction. No shuffles, no expf here.
__global__ __launch_bounds__(256) void k_conv1(const int* __restrict__ rowptr,
    const int* __restrict__ csr_src, const float* __restrict__ exf,
    const float* __restrict__ h1, const float* __restrict__ b1,
    float* __restrict__ hb)
{
  const int lane = threadIdx.x & 63;
  const int h = lane >> 4;
  const int n = (blockIdx.x * 256 + threadIdx.x) >> 6;
  const int row0 = __builtin_amdgcn_readfirstlane(rowptr[n]);
  const int row1 = __builtin_amdgcn_readfirstlane(rowptr[n + 1]);
  float acc = 0.f, den = 0.f;
  #pragma unroll 4
  for (int j = row0; j < row1; ++j){
    int s = csr_src[j];                       // wave-uniform -> s_load, sequential
    float eh = exf[(size_t)4 * j + h];        // 4B, streams through L1
    den += eh;
    acc = fmaf(h1[(size_t)s * HID + lane], eh, acc);
  }
  float o = acc / (den + 1e-16f) + b1[lane];
  hb[(size_t)n * HID + lane] = eluf(o);
}

// h2 = h @ W2 (64x64) + scalar-head attention logits
__global__ __launch_bounds__(256) void k_gemm2(const float* __restrict__ h,
    const float* __restrict__ W2, const float* __restrict__ asw,
    const float* __restrict__ adw, float* __restrict__ h2,
    float* __restrict__ as2, float* __restrict__ ad2)
{
  const int lane = threadIdx.x & 63;
  const int wid  = (blockIdx.x * 256 + threadIdx.x) >> 6;
  const int n0   = __builtin_amdgcn_readfirstlane(wid * 4);
  const float* hr = h + (size_t)n0 * HID;
  float a0 = 0.f, a1 = 0.f, a2 = 0.f, a3 = 0.f;
  #pragma unroll 4
  for (int k = 0; k < HID; ++k){
    const float w = W2[k * HID + lane];
    a0 = fmaf(hr[k],          w, a0);
    a1 = fmaf(hr[HID + k],    w, a1);
    a2 = fmaf(hr[2*HID + k],  w, a2);
    a3 = fmaf(hr[3*HID + k],  w, a3);
  }
  const float sw = asw[lane], dw = adw[lane];
  float acc[4] = {a0, a1, a2, a3};
  #pragma unroll
  for (int i = 0; i < 4; ++i){
    const int n = n0 + i;
    h2[(size_t)n * HID + lane] = acc[i];
    float ps = wsum64(acc[i] * sw);
    float pd = wsum64(acc[i] * dw);
    if (lane == 0){ as2[n] = ps; ad2[n] = pd; }
  }
}

__global__ __launch_bounds__(256) void k_att2(const int* __restrict__ csr_src,
    const int* __restrict__ csr_dst, const float* __restrict__ as2,
    const float* __restrict__ ad2, float* __restrict__ ex2)
{
  int i = blockIdx.x * 256 + threadIdx.x;
  if (i >= ET) return;
  ex2[i] = expf(lrelu(as2[csr_src[i]] + ad2[csr_dst[i]]));
}

// conv2 single-pass + fused residual + LayerNorm + elu + pool logit.
// hf aliases hb: each wave reads its own hres value before overwriting it.
__global__ __launch_bounds__(256) void k_conv2(const int* __restrict__ rowptr,
    const int* __restrict__ csr_src, const float* __restrict__ ex2,
    const float* __restrict__ h2, const float* __restrict__ b2,
    float* __restrict__ hb /* hres in, hf out */,
    const float* __restrict__ lng, const float* __restrict__ lnb,
    const float* __restrict__ wpool, const float* __restrict__ bpool,
    float* __restrict__ es)
{
  const int lane = threadIdx.x & 63;
  const int n = (blockIdx.x * 256 + threadIdx.x) >> 6;
  const int row0 = __builtin_amdgcn_readfirstlane(rowptr[n]);
  const int row1 = __builtin_amdgcn_readfirstlane(rowptr[n + 1]);
  float acc = 0.f, den = 0.f;
  #pragma unroll 4
  for (int j = row0; j < row1; ++j){
    int s = csr_src[j];        // s_load
    float e = ex2[j];          // wave-uniform -> s_load
    den += e;
    acc = fmaf(h2[(size_t)s * HID + lane], e, acc);
  }
  const size_t idxn = (size_t)n * HID + lane;
  float t = acc / (den + 1e-16f) + b2[lane] + hb[idxn];
  float mu  = wsum64(t) * (1.f / 64.f);
  float dv  = t - mu;
  float var = wsum64(dv * dv) * (1.f / 64.f);
  float hv = dv * (1.f / sqrtf(var + 1e-5f)) * lng[lane] + lnb[lane];
  hv = eluf(hv);
  hb[idxn] = hv;
  float sl = wsum64(hv * wpool[lane]) + bpool[0];
  if (lane == 0) es[n] = expf(sl);   // global softmax: max-shift dropped
}

__global__ __launch_bounds__(256) void k_sumes(const float* __restrict__ es,
                                               float* __restrict__ S)
{
  float v = 0.f;
  for (int i = blockIdx.x * 256 + threadIdx.x; i < NN; i += gridDim.x * 256)
    v += es[i];
  v = wsum64(v);
  __shared__ float red[4];
  if ((threadIdx.x & 63) == 0) red[threadIdx.x >> 6] = v;
  __syncthreads();
  if (threadIdx.x == 0) atomicAdd(S, red[0] + red[1] + red[2] + red[3]);
}

__global__ __launch_bounds__(256) void k_pool(const float* __restrict__ hf,
    const float* __restrict__ es, const int* __restrict__ batch,
    const float* __restrict__ S, float* __restrict__ pooled)
{
  const int lane = threadIdx.x & 63;
  const int wseg = blockIdx.x * 4 + (threadIdx.x >> 6);
  const int base = wseg * 64;
  if (base >= NN) return;
  const float invS = 1.f / S[0];
  int end = base + 64; if (end > NN) end = NN;
  float acc = 0.f;
  int gprev = batch[base];
  for (int n = base; n < end; ++n){
    int g = batch[n];
    if (g != gprev){
      atomicAdd(&pooled[gprev * HID + lane], acc);
      acc = 0.f; gprev = g;
    }
    acc = fmaf(hf[(size_t)n * HID + lane], es[n] * invS, acc);
  }
  atomicAdd(&pooled[gprev * HID + lane], acc);
}

__global__ __launch_bounds__(64) void k_head(const float* __restrict__ pooled,
    const float* __restrict__ wfc1, const float* __restrict__ bfc1,
    const float* __restrict__ wfc2, const float* __restrict__ bfc2,
    float* __restrict__ out)
{
  const int g = blockIdx.x, j = threadIdx.x;
  const float* pr = pooled + g * HID;
  float acc = bfc1[j];
  #pragma unroll 4
  for (int k = 0; k < HID; ++k) acc = fmaf(pr[k], wfc1[k * HID + j], acc);
  float z = eluf(acc);
  float r = wsum64(z * wfc2[j]);
  if (j == 0) out[g] = r + bfc2[0];
}

extern "C" void kernel_launch(void* const* d_in, const int* in_sizes, int n_in,
                              void* d_out, int out_size, void* d_ws, size_t ws_size,
                              hipStream_t stream)
{
  const float* x     = (const float*)d_in[0];
  const int*   ei    = (const int*)d_in[1];
  const int*   batch = (const int*)d_in[2];
  const float* W1    = (const float*)d_in[4];
  const float* asw1  = (const float*)d_in[5];
  const float* adw1  = (const float*)d_in[6];
  const float* b1    = (const float*)d_in[7];
  const float* W2    = (const float*)d_in[8];
  const float* asw2  = (const float*)d_in[9];
  const float* adw2  = (const float*)d_in[10];
  const float* b2    = (const float*)d_in[11];
  const float* lng   = (const float*)d_in[12];
  const float* lnb   = (const float*)d_in[13];
  const float* wpool = (const float*)d_in[14];
  const float* bpool = (const float*)d_in[15];
  const float* wfc1  = (const float*)d_in[16];
  const float* bfc1  = (const float*)d_in[17];
  const float* wfc2  = (const float*)d_in[18];
  const float* bfc2  = (const float*)d_in[19];

  float* ws = (float*)d_ws;
  float* h1     = ws;               // NN*64 (reused as h2 after conv1 reads it)
  float* hb     = ws +  6400000;    // conv1 out -> residual -> final hf (in place)
  float* ex1    = ws + 12800000;    // ET*4 (first ET floats reused as ex2)
  float* as1    = ws + 19600000;    // NN*4
  float* ad1    = ws + 20000000;    // NN*4
  float* as2    = ws + 20400000;    // NN
  float* ad2    = ws + 20500000;    // NN
  float* es     = ws + 20600000;    // NN
  float* pooled = ws + 20700000;    // 64*64
  float* Ssum   = ws + 20704096;    // 1
  int* iw       = (int*)(ws + 20704100);
  int* rowptr   = iw;               // NN+1 (pad 100004)
  int* cursor   = iw + 100004;      // NN
  int* deg      = iw + 200008;      // NN
  int* bsum     = iw + 300008;      // 512
  int* boff     = iw + 300520;      // 512
  int* csr_src  = iw + 301032;      // ET
  int* csr_dst  = iw + 2001032;     // ET
  // total ~24.4M words = 97.7 MB of d_ws

  hipMemsetAsync(deg, 0, (size_t)NN * 4, stream);
  hipMemsetAsync(pooled, 0, (size_t)NGR * 64 * 4, stream);
  hipMemsetAsync(Ssum, 0, 4, stream);

  // CSR build
  k_deg    <<<(ET + 255) / 256, 256, 0, stream>>>(ei, deg);
  k_scanA  <<<NB_SCAN, 256, 0, stream>>>(deg, rowptr, bsum);
  k_scanB  <<<1, 512, 0, stream>>>(bsum, boff);
  k_scanC  <<<NB_SCAN, 256, 0, stream>>>(rowptr, boff, cursor);
  k_scatter<<<(ET + 255) / 256, 256, 0, stream>>>(ei, cursor, csr_src, csr_dst);

  k_gemm1<<<6250, 256, 0, stream>>>(x, W1, asw1, adw1, h1, as1, ad1);
  k_att1 <<<(ET + 255) / 256, 256, 0, stream>>>(csr_src, csr_dst,
                                                (const float4*)as1,
                                                (const float4*)ad1, (float4*)ex1);
  k_conv1<<<25000, 256, 0, stream>>>(rowptr, csr_src, ex1, h1, b1, hb);
  k_gemm2<<<6250, 256, 0, stream>>>(hb, W2, asw2, adw2, h1, as2, ad2);
  k_att2 <<<(ET + 255) / 256, 256, 0, stream>>>(csr_src, csr_dst, as2, ad2, ex1);
  k_conv2<<<25000, 256, 0, stream>>>(rowptr, csr_src, ex1, h1, b2, hb,
                                     lng, lnb, wpool, bpool, es);
  k_sumes<<<128, 256, 0, stream>>>(es, Ssum);
  k_pool <<<391, 256, 0, stream>>>(hb, es, batch, Ssum, pooled);
  k_head <<<64, 64, 0, stream>>>(pooled, wfc1, bfc1, wfc2, bfc2, (float*)d_out);
}

// Round 4
// 423.958 us; speedup vs baseline: 3.1655x; 1.1206x over previous
//
#include <hip/hip_runtime.h>
#include <math.h>

#define NN 100000
#define NE 1600000      // edges WITHOUT self-loops; self-loop handled analytically
#define ICH 128
#define HID 64
#define NGR 64
#define NB_SCAN 391     // ceil(100000/256)
#define NWIN 8
#define WIN 12500       // NN / NWIN

__device__ __forceinline__ float lrelu(float x){ return x > 0.f ? x : 0.2f*x; }
__device__ __forceinline__ float eluf(float x){ return x > 0.f ? x : expm1f(x); }

__device__ __forceinline__ float wsum64(float v){
  #pragma unroll
  for (int m = 32; m >= 1; m >>= 1) v += __shfl_xor(v, m);
  return v;
}
__device__ __forceinline__ float wsum16(float v){
  v += __shfl_xor(v, 8); v += __shfl_xor(v, 4);
  v += __shfl_xor(v, 2); v += __shfl_xor(v, 1);
  return v;
}
__device__ __forceinline__ int wscan_incl(int v){
  const int lane = threadIdx.x & 63;
  #pragma unroll
  for (int d = 1; d < 64; d <<= 1){
    int t = __shfl_up(v, d);
    if (lane >= d) v += t;
  }
  return v;
}

// ---------------- CSR build (XCD-windowed by dst) ----------------
// blockIdx&7 selects a dst-window; that window's deg/cursor/csr lines stay in
// ONE XCD's L2 (round-robin dispatch) -> atomics L2-local, scatter lines
// accumulate fully before write-back. Cost: 8x streaming re-read of ei (L3).
__global__ __launch_bounds__(256) void k_deg(const int* __restrict__ ei_dst,
                                             int* __restrict__ deg)
{
  const int lo = (blockIdx.x & 7) * WIN, hi = lo + WIN;
  const int nb = gridDim.x >> 3, ib = blockIdx.x >> 3;
  for (int e = ib * 256 + threadIdx.x; e < NE; e += nb * 256){
    int d = ei_dst[e];
    if (d >= lo && d < hi) atomicAdd(&deg[d], 1);
  }
}

__global__ __launch_bounds__(256) void k_scanA(const int* __restrict__ deg,
    int* __restrict__ rowptr, int* __restrict__ bsum)
{
  int i = blockIdx.x * 256 + threadIdx.x;
  int v = (i < NN) ? deg[i] : 0;
  int incl = wscan_incl(v);
  __shared__ int wsums[4];
  int w = threadIdx.x >> 6, lane = threadIdx.x & 63;
  if (lane == 63) wsums[w] = incl;
  __syncthreads();
  int off = 0;
  for (int k = 0; k < w; ++k) off += wsums[k];
  if (i < NN) rowptr[i] = incl - v + off;
  if (threadIdx.x == 255) bsum[blockIdx.x] = off + incl;
}

__global__ __launch_bounds__(512) void k_scanB(const int* __restrict__ bsum,
                                               int* __restrict__ boff)
{
  int i = threadIdx.x;
  int v = (i < NB_SCAN) ? bsum[i] : 0;
  int incl = wscan_incl(v);
  __shared__ int wsums[8];
  int w = threadIdx.x >> 6, lane = threadIdx.x & 63;
  if (lane == 63) wsums[w] = incl;
  __syncthreads();
  int off = 0;
  for (int k = 0; k < w; ++k) off += wsums[k];
  if (i < NB_SCAN) boff[i] = incl - v + off;
}

__global__ __launch_bounds__(256) void k_scanC(int* __restrict__ rowptr,
    const int* __restrict__ boff, int* __restrict__ cursor)
{
  int i = blockIdx.x * 256 + threadIdx.x;
  if (i < NN){
    int val = rowptr[i] + boff[blockIdx.x];
    rowptr[i] = val;
    cursor[i] = val;
  }
  if (i == 0) rowptr[NN] = NE;
}

__global__ __launch_bounds__(256) void k_scatter(const int* __restrict__ ei,
    int* __restrict__ cursor, int* __restrict__ csr_src)
{
  const int lo = (blockIdx.x & 7) * WIN, hi = lo + WIN;
  const int nb = gridDim.x >> 3, ib = blockIdx.x >> 3;
  for (int e = ib * 256 + threadIdx.x; e < NE; e += nb * 256){
    int d = ei[NE + e];
    if (d >= lo && d < hi){
      int pos = atomicAdd(&cursor[d], 1);
      csr_src[pos] = ei[e];
    }
  }
}

// ---------------- dense node kernels ----------------
// h1 = x @ W1 (100000x128 * 128x64) + per-head attention logits
__global__ __launch_bounds__(256) void k_gemm1(const float* __restrict__ x,
    const float* __restrict__ W1, const float* __restrict__ asw,
    const float* __restrict__ adw, float* __restrict__ h1,
    float* __restrict__ as1, float* __restrict__ ad1)
{
  const int lane = threadIdx.x & 63;
  const int wid  = (blockIdx.x * 256 + threadIdx.x) >> 6;   // 0..24999
  const int n0   = __builtin_amdgcn_readfirstlane(wid * 4);
  const float* xr = x + (size_t)n0 * ICH;
  float a0 = 0.f, a1 = 0.f, a2 = 0.f, a3 = 0.f;
  #pragma unroll 4
  for (int k = 0; k < ICH; ++k){
    const float w = W1[k * HID + lane];
    a0 = fmaf(xr[k],          w, a0);
    a1 = fmaf(xr[ICH + k],    w, a1);
    a2 = fmaf(xr[2*ICH + k],  w, a2);
    a3 = fmaf(xr[3*ICH + k],  w, a3);
  }
  const float sw = asw[lane], dw = adw[lane];  // att layout [H][16] flattens to [64]
  float acc[4] = {a0, a1, a2, a3};
  #pragma unroll
  for (int i = 0; i < 4; ++i){
    const int n = n0 + i;
    h1[(size_t)n * HID + lane] = acc[i];
    float ps = wsum16(acc[i] * sw);
    float pd = wsum16(acc[i] * dw);
    if ((lane & 15) == 0){
      as1[n * 4 + (lane >> 4)] = ps;
      ad1[n * 4 + (lane >> 4)] = pd;
    }
  }
}

// conv1: single pass, attention fused (lane computes only its head's expf),
// self-loop handled analytically. out = (Sigma ex_e*h1[s]) / (Sigma ex_e).
__global__ __launch_bounds__(256) void k_conv1(const int* __restrict__ rowptr,
    const int* __restrict__ csr_src, const float* __restrict__ as1,
    const float* __restrict__ ad1, const float* __restrict__ h1,
    const float* __restrict__ b1, float* __restrict__ hb)
{
  const int lane = threadIdx.x & 63;
  const int h = lane >> 4;
  const int n = (blockIdx.x * 256 + threadIdx.x) >> 6;
  const int row0 = __builtin_amdgcn_readfirstlane(rowptr[n]);
  const int row1 = __builtin_amdgcn_readfirstlane(rowptr[n + 1]);
  const float adh = ad1[4 * n + h];
  // self-loop
  float eh = __expf(lrelu(as1[4 * n + h] + adh));
  float den = eh;
  float acc = eh * h1[(size_t)n * HID + lane];
  #pragma unroll 4
  for (int j = row0; j < row1; ++j){
    int s = csr_src[j];                            // wave-uniform -> s_load
    float e = __expf(lrelu(as1[4 * s + h] + adh)); // 4B broadcast gather
    den += e;
    acc = fmaf(h1[(size_t)s * HID + lane], e, acc);
  }
  float o = acc / (den + 1e-16f) + b1[lane];
  hb[(size_t)n * HID + lane] = eluf(o);
}

// h2 = h @ W2 (64x64) + scalar-head attention logits
__global__ __launch_bounds__(256) void k_gemm2(const float* __restrict__ h,
    const float* __restrict__ W2, const float* __restrict__ asw,
    const float* __restrict__ adw, float* __restrict__ h2,
    float* __restrict__ as2, float* __restrict__ ad2)
{
  const int lane = threadIdx.x & 63;
  const int wid  = (blockIdx.x * 256 + threadIdx.x) >> 6;
  const int n0   = __builtin_amdgcn_readfirstlane(wid * 4);
  const float* hr = h + (size_t)n0 * HID;
  float a0 = 0.f, a1 = 0.f, a2 = 0.f, a3 = 0.f;
  #pragma unroll 4
  for (int k = 0; k < HID; ++k){
    const float w = W2[k * HID + lane];
    a0 = fmaf(hr[k],          w, a0);
    a1 = fmaf(hr[HID + k],    w, a1);
    a2 = fmaf(hr[2*HID + k],  w, a2);
    a3 = fmaf(hr[3*HID + k],  w, a3);
  }
  const float sw = asw[lane], dw = adw[lane];
  float acc[4] = {a0, a1, a2, a3};
  #pragma unroll
  for (int i = 0; i < 4; ++i){
    const int n = n0 + i;
    h2[(size_t)n * HID + lane] = acc[i];
    float ps = wsum64(acc[i] * sw);
    float pd = wsum64(acc[i] * dw);
    if (lane == 0){ as2[n] = ps; ad2[n] = pd; }
  }
}

// conv2: single pass, fused attention + residual + LayerNorm + elu + pool logit.
// hf aliases hb: each wave reads its own residual before overwriting it.
__global__ __launch_bounds__(256) void k_conv2(const int* __restrict__ rowptr,
    const int* __restrict__ csr_src, const float* __restrict__ as2,
    const float* __restrict__ ad2, const float* __restrict__ h2,
    const float* __restrict__ b2, float* __restrict__ hb,
    const float* __restrict__ lng, const float* __restrict__ lnb,
    const float* __restrict__ wpool, const float* __restrict__ bpool,
    float* __restrict__ es)
{
  const int lane = threadIdx.x & 63;
  const int n = (blockIdx.x * 256 + threadIdx.x) >> 6;
  const int row0 = __builtin_amdgcn_readfirstlane(rowptr[n]);
  const int row1 = __builtin_amdgcn_readfirstlane(rowptr[n + 1]);
  const float adn = ad2[n];
  float eh = __expf(lrelu(as2[n] + adn));        // self-loop
  float den = eh;
  float acc = eh * h2[(size_t)n * HID + lane];
  #pragma unroll 4
  for (int j = row0; j < row1; ++j){
    int s = csr_src[j];                          // s_load
    float e = __expf(lrelu(as2[s] + adn));       // 4B all-lane broadcast
    den += e;
    acc = fmaf(h2[(size_t)s * HID + lane], e, acc);
  }
  const size_t idxn = (size_t)n * HID + lane;
  float t = acc / (den + 1e-16f) + b2[lane] + hb[idxn];
  float mu  = wsum64(t) * (1.f / 64.f);
  float dv  = t - mu;
  float var = wsum64(dv * dv) * (1.f / 64.f);
  float hv = dv * (1.f / sqrtf(var + 1e-5f)) * lng[lane] + lnb[lane];
  hv = eluf(hv);
  hb[idxn] = hv;
  float sl = wsum64(hv * wpool[lane]) + bpool[0];
  if (lane == 0) es[n] = __expf(sl);   // global softmax: max-shift dropped
}

__global__ __launch_bounds__(256) void k_sumes(const float* __restrict__ es,
                                               float* __restrict__ S)
{
  float v = 0.f;
  for (int i = blockIdx.x * 256 + threadIdx.x; i < NN; i += gridDim.x * 256)
    v += es[i];
  v = wsum64(v);
  __shared__ float red[4];
  if ((threadIdx.x & 63) == 0) red[threadIdx.x >> 6] = v;
  __syncthreads();
  if (threadIdx.x == 0) atomicAdd(S, red[0] + red[1] + red[2] + red[3]);
}

__global__ __launch_bounds__(256) void k_pool(const float* __restrict__ hf,
    const float* __restrict__ es, const int* __restrict__ batch,
    const float* __restrict__ S, float* __restrict__ pooled)
{
  const int lane = threadIdx.x & 63;
  const int wseg = blockIdx.x * 4 + (threadIdx.x >> 6);
  const int base = wseg * 64;
  if (base >= NN) return;
  const float invS = 1.f / S[0];
  int end = base + 64; if (end > NN) end = NN;
  float acc = 0.f;
  int gprev = batch[base];
  for (int n = base; n < end; ++n){
    int g = batch[n];
    if (g != gprev){
      atomicAdd(&pooled[gprev * HID + lane], acc);
      acc = 0.f; gprev = g;
    }
    acc = fmaf(hf[(size_t)n * HID + lane], es[n] * invS, acc);
  }
  atomicAdd(&pooled[gprev * HID + lane], acc);
}

__global__ __launch_bounds__(64) void k_head(const float* __restrict__ pooled,
    const float* __restrict__ wfc1, const float* __restrict__ bfc1,
    const float* __restrict__ wfc2, const float* __restrict__ bfc2,
    float* __restrict__ out)
{
  const int g = blockIdx.x, j = threadIdx.x;
  const float* pr = pooled + g * HID;
  float acc = bfc1[j];
  #pragma unroll 4
  for (int k = 0; k < HID; ++k) acc = fmaf(pr[k], wfc1[k * HID + j], acc);
  float z = eluf(acc);
  float r = wsum64(z * wfc2[j]);
  if (j == 0) out[g] = r + bfc2[0];
}

extern "C" void kernel_launch(void* const* d_in, const int* in_sizes, int n_in,
                              void* d_out, int out_size, void* d_ws, size_t ws_size,
                              hipStream_t stream)
{
  const float* x     = (const float*)d_in[0];
  const int*   ei    = (const int*)d_in[1];
  const int*   batch = (const int*)d_in[2];
  const float* W1    = (const float*)d_in[4];
  const float* asw1  = (const float*)d_in[5];
  const float* adw1  = (const float*)d_in[6];
  const float* b1    = (const float*)d_in[7];
  const float* W2    = (const float*)d_in[8];
  const float* asw2  = (const float*)d_in[9];
  const float* adw2  = (const float*)d_in[10];
  const float* b2    = (const float*)d_in[11];
  const float* lng   = (const float*)d_in[12];
  const float* lnb   = (const float*)d_in[13];
  const float* wpool = (const float*)d_in[14];
  const float* bpool = (const float*)d_in[15];
  const float* wfc1  = (const float*)d_in[16];
  const float* bfc1  = (const float*)d_in[17];
  const float* wfc2  = (const float*)d_in[18];
  const float* bfc2  = (const float*)d_in[19];

  float* ws = (float*)d_ws;
  float* h1     = ws;               // NN*64 (reused as h2 after gemm2)
  float* hb     = ws +  6400000;    // conv1 out -> residual -> final hf (in place)
  float* as1    = ws + 12800000;    // NN*4
  float* ad1    = ws + 13200000;    // NN*4
  float* as2    = ws + 13600000;    // NN
  float* ad2    = ws + 13700000;    // NN
  float* es     = ws + 13800000;    // NN
  float* pooled = ws + 13900000;    // 64*64
  float* Ssum   = ws + 13904096;    // 1
  int* iw       = (int*)(ws + 13904100);
  int* rowptr   = iw;               // NN+1 (pad 100004)
  int* cursor   = iw + 100004;      // NN
  int* deg      = iw + 200008;      // NN
  int* bsum     = iw + 300008;      // 512
  int* boff     = iw + 300520;      // 512
  int* csr_src  = iw + 301032;      // NE
  // total ~15.8M words = 63.2 MB of d_ws

  hipMemsetAsync(deg, 0, (size_t)NN * 4, stream);
  hipMemsetAsync(pooled, 0, (size_t)NGR * 64 * 4, stream);
  hipMemsetAsync(Ssum, 0, 4, stream);

  // CSR build (self-loops excluded; handled analytically in conv)
  k_deg    <<<2048, 256, 0, stream>>>(ei + NE, deg);
  k_scanA  <<<NB_SCAN, 256, 0, stream>>>(deg, rowptr, bsum);
  k_scanB  <<<1, 512, 0, stream>>>(bsum, boff);
  k_scanC  <<<NB_SCAN, 256, 0, stream>>>(rowptr, boff, cursor);
  k_scatter<<<2048, 256, 0, stream>>>(ei, cursor, csr_src);

  k_gemm1<<<6250, 256, 0, stream>>>(x, W1, asw1, adw1, h1, as1, ad1);
  k_conv1<<<25000, 256, 0, stream>>>(rowptr, csr_src, as1, ad1, h1, b1, hb);
  k_gemm2<<<6250, 256, 0, stream>>>(hb, W2, asw2, adw2, h1, as2, ad2);
  k_conv2<<<25000, 256, 0, stream>>>(rowptr, csr_src, as2, ad2, h1, b2, hb,
                                     lng, lnb, wpool, bpool, es);
  k_sumes<<<128, 256, 0, stream>>>(es, Ssum);
  k_pool <<<391, 256, 0, stream>>>(hb, es, batch, Ssum, pooled);
  k_head <<<64, 64, 0, stream>>>(pooled, wfc1, bfc1, wfc2, bfc2, (float*)d_out);
}

// Round 5
// 416.287 us; speedup vs baseline: 3.2239x; 1.0184x over previous
//
#include <hip/hip_runtime.h>
#include <math.h>

#define NN 100000
#define NE 1600000      // edges WITHOUT self-loops; self-loop handled analytically
#define ICH 128
#define HID 64
#define NGR 64
#define NB_SCAN 391     // ceil(100000/256)
#define NWIN 8
#define WIN 12500       // NN / NWIN

__device__ __forceinline__ float lrelu(float x){ return x > 0.f ? x : 0.2f*x; }
__device__ __forceinline__ float eluf(float x){ return x > 0.f ? x : expm1f(x); }

__device__ __forceinline__ float wsum64(float v){
  #pragma unroll
  for (int m = 32; m >= 1; m >>= 1) v += __shfl_xor(v, m);
  return v;
}
__device__ __forceinline__ float wsum16(float v){
  v += __shfl_xor(v, 8); v += __shfl_xor(v, 4);
  v += __shfl_xor(v, 2); v += __shfl_xor(v, 1);
  return v;
}
__device__ __forceinline__ int wscan_incl(int v){
  const int lane = threadIdx.x & 63;
  #pragma unroll
  for (int d = 1; d < 64; d <<= 1){
    int t = __shfl_up(v, d);
    if (lane >= d) v += t;
  }
  return v;
}

// ---------------- CSR build (XCD-windowed by dst) ----------------
__global__ __launch_bounds__(256) void k_deg(const int* __restrict__ ei_dst,
                                             int* __restrict__ deg)
{
  const int lo = (blockIdx.x & 7) * WIN, hi = lo + WIN;
  const int nb = gridDim.x >> 3, ib = blockIdx.x >> 3;
  for (int e = ib * 256 + threadIdx.x; e < NE; e += nb * 256){
    int d = ei_dst[e];
    if (d >= lo && d < hi) atomicAdd(&deg[d], 1);
  }
}

__global__ __launch_bounds__(256) void k_scanA(const int* __restrict__ deg,
    int* __restrict__ rowptr, int* __restrict__ bsum)
{
  int i = blockIdx.x * 256 + threadIdx.x;
  int v = (i < NN) ? deg[i] : 0;
  int incl = wscan_incl(v);
  __shared__ int wsums[4];
  int w = threadIdx.x >> 6, lane = threadIdx.x & 63;
  if (lane == 63) wsums[w] = incl;
  __syncthreads();
  int off = 0;
  for (int k = 0; k < w; ++k) off += wsums[k];
  if (i < NN) rowptr[i] = incl - v + off;
  if (threadIdx.x == 255) bsum[blockIdx.x] = off + incl;
}

__global__ __launch_bounds__(512) void k_scanB(const int* __restrict__ bsum,
                                               int* __restrict__ boff)
{
  int i = threadIdx.x;
  int v = (i < NB_SCAN) ? bsum[i] : 0;
  int incl = wscan_incl(v);
  __shared__ int wsums[8];
  int w = threadIdx.x >> 6, lane = threadIdx.x & 63;
  if (lane == 63) wsums[w] = incl;
  __syncthreads();
  int off = 0;
  for (int k = 0; k < w; ++k) off += wsums[k];
  if (i < NB_SCAN) boff[i] = incl - v + off;
}

__global__ __launch_bounds__(256) void k_scanC(int* __restrict__ rowptr,
    const int* __restrict__ boff, int* __restrict__ cursor)
{
  int i = blockIdx.x * 256 + threadIdx.x;
  if (i < NN){
    int val = rowptr[i] + boff[blockIdx.x];
    rowptr[i] = val;
    cursor[i] = val;
  }
  if (i == 0) rowptr[NN] = NE;
}

__global__ __launch_bounds__(256) void k_scatter(const int* __restrict__ ei,
    int* __restrict__ cursor, int* __restrict__ csr_src)
{
  const int lo = (blockIdx.x & 7) * WIN, hi = lo + WIN;
  const int nb = gridDim.x >> 3, ib = blockIdx.x >> 3;
  for (int e = ib * 256 + threadIdx.x; e < NE; e += nb * 256){
    int d = ei[NE + e];
    if (d >= lo && d < hi){
      int pos = atomicAdd(&cursor[d], 1);
      csr_src[pos] = ei[e];
    }
  }
}

// ---------------- dense node kernels ----------------
// h1 = x @ W1 + per-head attention logits. x tile staged in LDS (coalesced
// float4), waves read rows via broadcast ds_read -> VALU stays fed (the old
// wave-uniform global reads became s_loads whose latency stalled the FMAs).
__global__ __launch_bounds__(256) void k_gemm1(const float* __restrict__ x,
    const float* __restrict__ W1, const float* __restrict__ asw,
    const float* __restrict__ adw, float* __restrict__ h1,
    float* __restrict__ as1, float* __restrict__ ad1)
{
  __shared__ float xs[16 * ICH];            // 8 KB
  const int t = threadIdx.x;
  const int n0 = blockIdx.x * 16;
  const float4* xg4 = (const float4*)(x + (size_t)n0 * ICH);
  float4* xs4 = (float4*)xs;
  xs4[t]       = xg4[t];
  xs4[t + 256] = xg4[t + 256];
  __syncthreads();

  const int lane = t & 63;
  const float* xr = xs + (t >> 6) * 4 * ICH;   // wave's 4 rows
  float a0 = 0.f, a1 = 0.f, a2 = 0.f, a3 = 0.f;
  #pragma unroll 8
  for (int k = 0; k < ICH; ++k){
    const float w = W1[k * HID + lane];
    a0 = fmaf(xr[k],          w, a0);
    a1 = fmaf(xr[ICH + k],    w, a1);
    a2 = fmaf(xr[2*ICH + k],  w, a2);
    a3 = fmaf(xr[3*ICH + k],  w, a3);
  }
  const float sw = asw[lane], dw = adw[lane];  // att layout [H][16] flattens to [64]
  const int nw = n0 + (t >> 6) * 4;
  float acc[4] = {a0, a1, a2, a3};
  #pragma unroll
  for (int i = 0; i < 4; ++i){
    const int n = nw + i;
    h1[(size_t)n * HID + lane] = acc[i];
    float ps = wsum16(acc[i] * sw);
    float pd = wsum16(acc[i] * dw);
    if ((lane & 15) == 0){
      as1[n * 4 + (lane >> 4)] = ps;
      ad1[n * 4 + (lane >> 4)] = pd;
    }
  }
}

// conv1: single pass, attention fused, self-loop analytic.
__global__ __launch_bounds__(256) void k_conv1(const int* __restrict__ rowptr,
    const int* __restrict__ csr_src, const float* __restrict__ as1,
    const float* __restrict__ ad1, const float* __restrict__ h1,
    const float* __restrict__ b1, float* __restrict__ hb)
{
  const int lane = threadIdx.x & 63;
  const int h = lane >> 4;
  const int n = (blockIdx.x * 256 + threadIdx.x) >> 6;
  const int row0 = __builtin_amdgcn_readfirstlane(rowptr[n]);
  const int row1 = __builtin_amdgcn_readfirstlane(rowptr[n + 1]);
  const float adh = ad1[4 * n + h];
  float eh = __expf(lrelu(as1[4 * n + h] + adh));   // self-loop
  float den = eh;
  float acc = eh * h1[(size_t)n * HID + lane];
  #pragma unroll 4
  for (int j = row0; j < row1; ++j){
    int s = csr_src[j];                            // wave-uniform -> s_load
    float e = __expf(lrelu(as1[4 * s + h] + adh));
    den += e;
    acc = fmaf(h1[(size_t)s * HID + lane], e, acc);
  }
  float o = acc / (den + 1e-16f) + b1[lane];
  hb[(size_t)n * HID + lane] = eluf(o);
}

// h2 = h @ W2 (64x64) + scalar-head attention logits; LDS-staged like gemm1.
__global__ __launch_bounds__(256) void k_gemm2(const float* __restrict__ h,
    const float* __restrict__ W2, const float* __restrict__ asw,
    const float* __restrict__ adw, float* __restrict__ h2,
    float* __restrict__ as2, float* __restrict__ ad2)
{
  __shared__ float hs[16 * HID];            // 4 KB
  const int t = threadIdx.x;
  const int n0 = blockIdx.x * 16;
  const float4* hg4 = (const float4*)(h + (size_t)n0 * HID);
  float4* hs4 = (float4*)hs;
  hs4[t] = hg4[t];                          // 16*64/4 = 256 float4
  __syncthreads();

  const int lane = t & 63;
  const float* hr = hs + (t >> 6) * 4 * HID;
  float a0 = 0.f, a1 = 0.f, a2 = 0.f, a3 = 0.f;
  #pragma unroll 8
  for (int k = 0; k < HID; ++k){
    const float w = W2[k * HID + lane];
    a0 = fmaf(hr[k],          w, a0);
    a1 = fmaf(hr[HID + k],    w, a1);
    a2 = fmaf(hr[2*HID + k],  w, a2);
    a3 = fmaf(hr[3*HID + k],  w, a3);
  }
  const float sw = asw[lane], dw = adw[lane];
  const int nw = n0 + (t >> 6) * 4;
  float acc[4] = {a0, a1, a2, a3};
  #pragma unroll
  for (int i = 0; i < 4; ++i){
    const int n = nw + i;
    h2[(size_t)n * HID + lane] = acc[i];
    float ps = wsum64(acc[i] * sw);
    float pd = wsum64(acc[i] * dw);
    if (lane == 0){ as2[n] = ps; ad2[n] = pd; }
  }
}

// conv2: single pass + fused residual + LayerNorm + elu + pool logit.
__global__ __launch_bounds__(256) void k_conv2(const int* __restrict__ rowptr,
    const int* __restrict__ csr_src, const float* __restrict__ as2,
    const float* __restrict__ ad2, const float* __restrict__ h2,
    const float* __restrict__ b2, float* __restrict__ hb,
    const float* __restrict__ lng, const float* __restrict__ lnb,
    const float* __restrict__ wpool, const float* __restrict__ bpool,
    float* __restrict__ es)
{
  const int lane = threadIdx.x & 63;
  const int n = (blockIdx.x * 256 + threadIdx.x) >> 6;
  const int row0 = __builtin_amdgcn_readfirstlane(rowptr[n]);
  const int row1 = __builtin_amdgcn_readfirstlane(rowptr[n + 1]);
  const float adn = ad2[n];
  float eh = __expf(lrelu(as2[n] + adn));        // self-loop
  float den = eh;
  float acc = eh * h2[(size_t)n * HID + lane];
  #pragma unroll 4
  for (int j = row0; j < row1; ++j){
    int s = csr_src[j];
    float e = __expf(lrelu(as2[s] + adn));
    den += e;
    acc = fmaf(h2[(size_t)s * HID + lane], e, acc);
  }
  const size_t idxn = (size_t)n * HID + lane;
  float t = acc / (den + 1e-16f) + b2[lane] + hb[idxn];
  float mu  = wsum64(t) * (1.f / 64.f);
  float dv  = t - mu;
  float var = wsum64(dv * dv) * (1.f / 64.f);
  float hv = dv * (1.f / sqrtf(var + 1e-5f)) * lng[lane] + lnb[lane];
  hv = eluf(hv);
  hb[idxn] = hv;
  float sl = wsum64(hv * wpool[lane]) + bpool[0];
  if (lane == 0) es[n] = __expf(sl);   // global softmax: max-shift dropped
}

__global__ __launch_bounds__(256) void k_sumes(const float* __restrict__ es,
                                               float* __restrict__ S)
{
  float v = 0.f;
  for (int i = blockIdx.x * 256 + threadIdx.x; i < NN; i += gridDim.x * 256)
    v += es[i];
  v = wsum64(v);
  __shared__ float red[4];
  if ((threadIdx.x & 63) == 0) red[threadIdx.x >> 6] = v;
  __syncthreads();
  if (threadIdx.x == 0) atomicAdd(S, red[0] + red[1] + red[2] + red[3]);
}

__global__ __launch_bounds__(256) void k_pool(const float* __restrict__ hf,
    const float* __restrict__ es, const int* __restrict__ batch,
    const float* __restrict__ S, float* __restrict__ pooled)
{
  const int lane = threadIdx.x & 63;
  const int wseg = blockIdx.x * 4 + (threadIdx.x >> 6);
  const int base = wseg * 64;
  if (base >= NN) return;
  const float invS = 1.f / S[0];
  int end = base + 64; if (end > NN) end = NN;
  float acc = 0.f;
  int gprev = batch[base];
  for (int n = base; n < end; ++n){
    int g = batch[n];
    if (g != gprev){
      atomicAdd(&pooled[gprev * HID + lane], acc);
      acc = 0.f; gprev = g;
    }
    acc = fmaf(hf[(size_t)n * HID + lane], es[n] * invS, acc);
  }
  atomicAdd(&pooled[gprev * HID + lane], acc);
}

__global__ __launch_bounds__(64) void k_head(const float* __restrict__ pooled,
    const float* __restrict__ wfc1, const float* __restrict__ bfc1,
    const float* __restrict__ wfc2, const float* __restrict__ bfc2,
    float* __restrict__ out)
{
  const int g = blockIdx.x, j = threadIdx.x;
  const float* pr = pooled + g * HID;
  float acc = bfc1[j];
  #pragma unroll 4
  for (int k = 0; k < HID; ++k) acc = fmaf(pr[k], wfc1[k * HID + j], acc);
  float z = eluf(acc);
  float r = wsum64(z * wfc2[j]);
  if (j == 0) out[g] = r + bfc2[0];
}

extern "C" void kernel_launch(void* const* d_in, const int* in_sizes, int n_in,
                              void* d_out, int out_size, void* d_ws, size_t ws_size,
                              hipStream_t stream)
{
  const float* x     = (const float*)d_in[0];
  const int*   ei    = (const int*)d_in[1];
  const int*   batch = (const int*)d_in[2];
  const float* W1    = (const float*)d_in[4];
  const float* asw1  = (const float*)d_in[5];
  const float* adw1  = (const float*)d_in[6];
  const float* b1    = (const float*)d_in[7];
  const float* W2    = (const float*)d_in[8];
  const float* asw2  = (const float*)d_in[9];
  const float* adw2  = (const float*)d_in[10];
  const float* b2    = (const float*)d_in[11];
  const float* lng   = (const float*)d_in[12];
  const float* lnb   = (const float*)d_in[13];
  const float* wpool = (const float*)d_in[14];
  const float* bpool = (const float*)d_in[15];
  const float* wfc1  = (const float*)d_in[16];
  const float* bfc1  = (const float*)d_in[17];
  const float* wfc2  = (const float*)d_in[18];
  const float* bfc2  = (const float*)d_in[19];

  float* ws = (float*)d_ws;
  float* h1     = ws;               // NN*64 (reused as h2 after gemm2)
  float* hb     = ws +  6400000;    // conv1 out -> residual -> final hf (in place)
  float* as1    = ws + 12800000;    // NN*4
  float* ad1    = ws + 13200000;    // NN*4
  float* as2    = ws + 13600000;    // NN
  float* ad2    = ws + 13700000;    // NN
  float* es     = ws + 13800000;    // NN
  float* pooled = ws + 13900000;    // 64*64
  float* Ssum   = ws + 13904096;    // 1
  int* iw       = (int*)(ws + 13904100);
  int* rowptr   = iw;               // NN+1 (pad 100004)
  int* cursor   = iw + 100004;      // NN
  int* deg      = iw + 200008;      // NN
  int* bsum     = iw + 300008;      // 512
  int* boff     = iw + 300520;      // 512
  int* csr_src  = iw + 301032;      // NE
  // total ~15.8M words = 63.2 MB of d_ws

  hipMemsetAsync(deg, 0, (size_t)NN * 4, stream);
  hipMemsetAsync(pooled, 0, (size_t)NGR * 64 * 4, stream);
  hipMemsetAsync(Ssum, 0, 4, stream);

  // CSR build (self-loops excluded; handled analytically in conv)
  k_deg    <<<2048, 256, 0, stream>>>(ei + NE, deg);
  k_scanA  <<<NB_SCAN, 256, 0, stream>>>(deg, rowptr, bsum);
  k_scanB  <<<1, 512, 0, stream>>>(bsum, boff);
  k_scanC  <<<NB_SCAN, 256, 0, stream>>>(rowptr, boff, cursor);
  k_scatter<<<2048, 256, 0, stream>>>(ei, cursor, csr_src);

  k_gemm1<<<6250, 256, 0, stream>>>(x, W1, asw1, adw1, h1, as1, ad1);
  k_conv1<<<25000, 256, 0, stream>>>(rowptr, csr_src, as1, ad1, h1, b1, hb);
  k_gemm2<<<6250, 256, 0, stream>>>(hb, W2, asw2, adw2, h1, as2, ad2);
  k_conv2<<<25000, 256, 0, stream>>>(rowptr, csr_src, as2, ad2, h1, b2, hb,
                                     lng, lnb, wpool, bpool, es);
  k_sumes<<<128, 256, 0, stream>>>(es, Ssum);
  k_pool <<<391, 256, 0, stream>>>(hb, es, batch, Ssum, pooled);
  k_head <<<64, 64, 0, stream>>>(pooled, wfc1, bfc1, wfc2, bfc2, (float*)d_out);
}

// Round 6
// 405.073 us; speedup vs baseline: 3.3131x; 1.0277x over previous
//
#include <hip/hip_runtime.h>
#include <math.h>

#define NN 100000
#define NE 1600000      // edges WITHOUT self-loops; self-loop handled analytically
#define ICH 128
#define HID 64
#define NGR 64
#define NB_SCAN 391     // ceil(100000/256)

__device__ __forceinline__ float lrelu(float x){ return x > 0.f ? x : 0.2f*x; }
__device__ __forceinline__ float eluf(float x){ return x > 0.f ? x : expm1f(x); }

__device__ __forceinline__ float bf2f(unsigned short u){
  return __uint_as_float(((unsigned int)u) << 16);
}
__device__ __forceinline__ unsigned short f2bf(float f){   // RNE
  unsigned int u = __float_as_uint(f);
  return (unsigned short)((u + 0x7FFF + ((u >> 16) & 1)) >> 16);
}

__device__ __forceinline__ float wsum64(float v){
  #pragma unroll
  for (int m = 32; m >= 1; m >>= 1) v += __shfl_xor(v, m);
  return v;
}
__device__ __forceinline__ float wsum16(float v){
  v += __shfl_xor(v, 8); v += __shfl_xor(v, 4);
  v += __shfl_xor(v, 2); v += __shfl_xor(v, 1);
  return v;
}
__device__ __forceinline__ int wscan_incl(int v){
  const int lane = threadIdx.x & 63;
  #pragma unroll
  for (int d = 1; d < 64; d <<= 1){
    int t = __shfl_up(v, d);
    if (lane >= d) v += t;
  }
  return v;
}

// ---------------- CSR build (XCD/L2-windowed by dst) ----------------
// 4 dst-windows: per-window hot set (deg slice 100KB) stays cache-local;
// 4x streaming re-read of dst array is L3-served.
__global__ __launch_bounds__(256) void k_deg(const int* __restrict__ ei_dst,
                                             int* __restrict__ deg)
{
  const int lo = (blockIdx.x & 3) * 25000, hi = lo + 25000;
  const int nb = gridDim.x >> 2, ib = blockIdx.x >> 2;
  for (int e = ib * 256 + threadIdx.x; e < NE; e += nb * 256){
    int d = ei_dst[e];
    if (d >= lo && d < hi) atomicAdd(&deg[d], 1);
  }
}

__global__ __launch_bounds__(256) void k_scanA(const int* __restrict__ deg,
    int* __restrict__ rowptr, int* __restrict__ bsum)
{
  int i = blockIdx.x * 256 + threadIdx.x;
  int v = (i < NN) ? deg[i] : 0;
  int incl = wscan_incl(v);
  __shared__ int wsums[4];
  int w = threadIdx.x >> 6, lane = threadIdx.x & 63;
  if (lane == 63) wsums[w] = incl;
  __syncthreads();
  int off = 0;
  for (int k = 0; k < w; ++k) off += wsums[k];
  if (i < NN) rowptr[i] = incl - v + off;
  if (threadIdx.x == 255) bsum[blockIdx.x] = off + incl;
}

__global__ __launch_bounds__(512) void k_scanB(const int* __restrict__ bsum,
                                               int* __restrict__ boff)
{
  int i = threadIdx.x;
  int v = (i < NB_SCAN) ? bsum[i] : 0;
  int incl = wscan_incl(v);
  __shared__ int wsums[8];
  int w = threadIdx.x >> 6, lane = threadIdx.x & 63;
  if (lane == 63) wsums[w] = incl;
  __syncthreads();
  int off = 0;
  for (int k = 0; k < w; ++k) off += wsums[k];
  if (i < NB_SCAN) boff[i] = incl - v + off;
}

__global__ __launch_bounds__(256) void k_scanC(int* __restrict__ rowptr,
    const int* __restrict__ boff, int* __restrict__ cursor)
{
  int i = blockIdx.x * 256 + threadIdx.x;
  if (i < NN){
    int val = rowptr[i] + boff[blockIdx.x];
    rowptr[i] = val;
    cursor[i] = val;
  }
  if (i == 0) rowptr[NN] = NE;
}

// 8 windows: scatter target region per window ~800KB -> lines fill fully in
// one XCD's L2 before write-back; cursor atomics L2-local.
__global__ __launch_bounds__(256) void k_scatter(const int* __restrict__ ei,
    int* __restrict__ cursor, int* __restrict__ csr_src)
{
  const int lo = (blockIdx.x & 7) * 12500, hi = lo + 12500;
  const int nb = gridDim.x >> 3, ib = blockIdx.x >> 3;
  for (int e = ib * 256 + threadIdx.x; e < NE; e += nb * 256){
    int d = ei[NE + e];
    if (d >= lo && d < hi){
      int pos = atomicAdd(&cursor[d], 1);
      csr_src[pos] = ei[e];
    }
  }
}

// ---------------- dense node kernels ----------------
// h1 = x @ W1 + per-head attention logits; x tile staged in LDS.
// h1 is ONLY consumed by conv1's gathers -> store bf16 (halves gather bytes).
__global__ __launch_bounds__(256) void k_gemm1(const float* __restrict__ x,
    const float* __restrict__ W1, const float* __restrict__ asw,
    const float* __restrict__ adw, unsigned short* __restrict__ h1b,
    float* __restrict__ as1, float* __restrict__ ad1)
{
  __shared__ float xs[16 * ICH];            // 8 KB
  const int t = threadIdx.x;
  const int n0 = blockIdx.x * 16;
  const float4* xg4 = (const float4*)(x + (size_t)n0 * ICH);
  float4* xs4 = (float4*)xs;
  xs4[t]       = xg4[t];
  xs4[t + 256] = xg4[t + 256];
  __syncthreads();

  const int lane = t & 63;
  const float* xr = xs + (t >> 6) * 4 * ICH;   // wave's 4 rows
  float a0 = 0.f, a1 = 0.f, a2 = 0.f, a3 = 0.f;
  #pragma unroll 8
  for (int k = 0; k < ICH; ++k){
    const float w = W1[k * HID + lane];
    a0 = fmaf(xr[k],          w, a0);
    a1 = fmaf(xr[ICH + k],    w, a1);
    a2 = fmaf(xr[2*ICH + k],  w, a2);
    a3 = fmaf(xr[3*ICH + k],  w, a3);
  }
  const float sw = asw[lane], dw = adw[lane];  // att layout [H][16] flattens to [64]
  const int nw = n0 + (t >> 6) * 4;
  float acc[4] = {a0, a1, a2, a3};
  #pragma unroll
  for (int i = 0; i < 4; ++i){
    const int n = nw + i;
    h1b[(size_t)n * HID + lane] = f2bf(acc[i]);
    float ps = wsum16(acc[i] * sw);
    float pd = wsum16(acc[i] * dw);
    if ((lane & 15) == 0){
      as1[n * 4 + (lane >> 4)] = ps;
      ad1[n * 4 + (lane >> 4)] = pd;
    }
  }
}

// conv1: single pass, attention fused, self-loop analytic, bf16 gathers.
__global__ __launch_bounds__(256) void k_conv1(const int* __restrict__ rowptr,
    const int* __restrict__ csr_src, const float* __restrict__ as1,
    const float* __restrict__ ad1, const unsigned short* __restrict__ h1b,
    const float* __restrict__ b1, float* __restrict__ hb)
{
  const int lane = threadIdx.x & 63;
  const int h = lane >> 4;
  const int n = (blockIdx.x * 256 + threadIdx.x) >> 6;
  const int row0 = __builtin_amdgcn_readfirstlane(rowptr[n]);
  const int row1 = __builtin_amdgcn_readfirstlane(rowptr[n + 1]);
  const float adh = ad1[4 * n + h];
  float eh = __expf(lrelu(as1[4 * n + h] + adh));   // self-loop
  float den = eh;
  float acc = eh * bf2f(h1b[(size_t)n * HID + lane]);
  #pragma unroll 4
  for (int j = row0; j < row1; ++j){
    int s = csr_src[j];                            // wave-uniform -> s_load
    float e = __expf(lrelu(as1[4 * s + h] + adh));
    den += e;
    acc = fmaf(bf2f(h1b[(size_t)s * HID + lane]), e, acc);
  }
  float o = acc / (den + 1e-16f) + b1[lane];
  hb[(size_t)n * HID + lane] = eluf(o);
}

// h2 = h @ W2 (64x64) + scalar-head attention logits; LDS-staged; bf16 out.
__global__ __launch_bounds__(256) void k_gemm2(const float* __restrict__ h,
    const float* __restrict__ W2, const float* __restrict__ asw,
    const float* __restrict__ adw, unsigned short* __restrict__ h2b,
    float* __restrict__ as2, float* __restrict__ ad2)
{
  __shared__ float hs[16 * HID];            // 4 KB
  const int t = threadIdx.x;
  const int n0 = blockIdx.x * 16;
  const float4* hg4 = (const float4*)(h + (size_t)n0 * HID);
  float4* hs4 = (float4*)hs;
  hs4[t] = hg4[t];
  __syncthreads();

  const int lane = t & 63;
  const float* hr = hs + (t >> 6) * 4 * HID;
  float a0 = 0.f, a1 = 0.f, a2 = 0.f, a3 = 0.f;
  #pragma unroll 8
  for (int k = 0; k < HID; ++k){
    const float w = W2[k * HID + lane];
    a0 = fmaf(hr[k],          w, a0);
    a1 = fmaf(hr[HID + k],    w, a1);
    a2 = fmaf(hr[2*HID + k],  w, a2);
    a3 = fmaf(hr[3*HID + k],  w, a3);
  }
  const float sw = asw[lane], dw = adw[lane];
  const int nw = n0 + (t >> 6) * 4;
  float acc[4] = {a0, a1, a2, a3};
  #pragma unroll
  for (int i = 0; i < 4; ++i){
    const int n = nw + i;
    h2b[(size_t)n * HID + lane] = f2bf(acc[i]);
    float ps = wsum64(acc[i] * sw);
    float pd = wsum64(acc[i] * dw);
    if (lane == 0){ as2[n] = ps; ad2[n] = pd; }
  }
}

// conv2: single pass + fused residual + LayerNorm + elu + pool logit.
__global__ __launch_bounds__(256) void k_conv2(const int* __restrict__ rowptr,
    const int* __restrict__ csr_src, const float* __restrict__ as2,
    const float* __restrict__ ad2, const unsigned short* __restrict__ h2b,
    const float* __restrict__ b2, float* __restrict__ hb,
    const float* __restrict__ lng, const float* __restrict__ lnb,
    const float* __restrict__ wpool, const float* __restrict__ bpool,
    float* __restrict__ es)
{
  const int lane = threadIdx.x & 63;
  const int n = (blockIdx.x * 256 + threadIdx.x) >> 6;
  const int row0 = __builtin_amdgcn_readfirstlane(rowptr[n]);
  const int row1 = __builtin_amdgcn_readfirstlane(rowptr[n + 1]);
  const float adn = ad2[n];
  float eh = __expf(lrelu(as2[n] + adn));        // self-loop
  float den = eh;
  float acc = eh * bf2f(h2b[(size_t)n * HID + lane]);
  #pragma unroll 4
  for (int j = row0; j < row1; ++j){
    int s = csr_src[j];
    float e = __expf(lrelu(as2[s] + adn));
    den += e;
    acc = fmaf(bf2f(h2b[(size_t)s * HID + lane]), e, acc);
  }
  const size_t idxn = (size_t)n * HID + lane;
  float t = acc / (den + 1e-16f) + b2[lane] + hb[idxn];
  float mu  = wsum64(t) * (1.f / 64.f);
  float dv  = t - mu;
  float var = wsum64(dv * dv) * (1.f / 64.f);
  float hv = dv * (1.f / sqrtf(var + 1e-5f)) * lng[lane] + lnb[lane];
  hv = eluf(hv);
  hb[idxn] = hv;
  float sl = wsum64(hv * wpool[lane]) + bpool[0];
  if (lane == 0) es[n] = __expf(sl);   // global softmax: max-shift dropped
}

__global__ __launch_bounds__(256) void k_sumes(const float* __restrict__ es,
                                               float* __restrict__ S)
{
  float v = 0.f;
  for (int i = blockIdx.x * 256 + threadIdx.x; i < NN; i += gridDim.x * 256)
    v += es[i];
  v = wsum64(v);
  __shared__ float red[4];
  if ((threadIdx.x & 63) == 0) red[threadIdx.x >> 6] = v;
  __syncthreads();
  if (threadIdx.x == 0) atomicAdd(S, red[0] + red[1] + red[2] + red[3]);
}

__global__ __launch_bounds__(256) void k_pool(const float* __restrict__ hf,
    const float* __restrict__ es, const int* __restrict__ batch,
    const float* __restrict__ S, float* __restrict__ pooled)
{
  const int lane = threadIdx.x & 63;
  const int wseg = blockIdx.x * 4 + (threadIdx.x >> 6);
  const int base = wseg * 64;
  if (base >= NN) return;
  const float invS = 1.f / S[0];
  int end = base + 64; if (end > NN) end = NN;
  float acc = 0.f;
  int gprev = batch[base];
  for (int n = base; n < end; ++n){
    int g = batch[n];
    if (g != gprev){
      atomicAdd(&pooled[gprev * HID + lane], acc);
      acc = 0.f; gprev = g;
    }
    acc = fmaf(hf[(size_t)n * HID + lane], es[n] * invS, acc);
  }
  atomicAdd(&pooled[gprev * HID + lane], acc);
}

__global__ __launch_bounds__(64) void k_head(const float* __restrict__ pooled,
    const float* __restrict__ wfc1, const float* __restrict__ bfc1,
    const float* __restrict__ wfc2, const float* __restrict__ bfc2,
    float* __restrict__ out)
{
  const int g = blockIdx.x, j = threadIdx.x;
  const float* pr = pooled + g * HID;
  float acc = bfc1[j];
  #pragma unroll 4
  for (int k = 0; k < HID; ++k) acc = fmaf(pr[k], wfc1[k * HID + j], acc);
  float z = eluf(acc);
  float r = wsum64(z * wfc2[j]);
  if (j == 0) out[g] = r + bfc2[0];
}

extern "C" void kernel_launch(void* const* d_in, const int* in_sizes, int n_in,
                              void* d_out, int out_size, void* d_ws, size_t ws_size,
                              hipStream_t stream)
{
  const float* x     = (const float*)d_in[0];
  const int*   ei    = (const int*)d_in[1];
  const int*   batch = (const int*)d_in[2];
  const float* W1    = (const float*)d_in[4];
  const float* asw1  = (const float*)d_in[5];
  const float* adw1  = (const float*)d_in[6];
  const float* b1    = (const float*)d_in[7];
  const float* W2    = (const float*)d_in[8];
  const float* asw2  = (const float*)d_in[9];
  const float* adw2  = (const float*)d_in[10];
  const float* b2    = (const float*)d_in[11];
  const float* lng   = (const float*)d_in[12];
  const float* lnb   = (const float*)d_in[13];
  const float* wpool = (const float*)d_in[14];
  const float* bpool = (const float*)d_in[15];
  const float* wfc1  = (const float*)d_in[16];
  const float* bfc1  = (const float*)d_in[17];
  const float* wfc2  = (const float*)d_in[18];
  const float* bfc2  = (const float*)d_in[19];

  float* ws = (float*)d_ws;
  float* hb     = ws;               // NN*64 fp32: conv1 out -> residual -> hf
  float* as1    = ws +  6400000;    // NN*4
  float* ad1    = ws +  6800000;    // NN*4
  float* as2    = ws +  7200000;    // NN
  float* ad2    = ws +  7300000;    // NN
  float* es     = ws +  7400000;    // NN
  float* pooled = ws +  7500000;    // 64*64
  float* Ssum   = ws +  7504096;    // 1
  unsigned short* hub = (unsigned short*)(ws + 7504100);  // NN*64 bf16 (h1b, then h2b)
  int* iw       = (int*)(ws + 10704100);
  int* rowptr   = iw;               // NN+1 (pad 100004)
  int* cursor   = iw + 100004;      // NN
  int* deg      = iw + 200008;      // NN
  int* bsum     = iw + 300008;      // 512
  int* boff     = iw + 300520;      // 512
  int* csr_src  = iw + 301032;      // NE
  // total ~12.6M words = 50.4 MB of d_ws

  hipMemsetAsync(deg, 0, (size_t)NN * 4, stream);
  hipMemsetAsync(pooled, 0, (size_t)NGR * 64 * 4, stream);
  hipMemsetAsync(Ssum, 0, 4, stream);

  // CSR build (self-loops excluded; handled analytically in conv)
  k_deg    <<<2048, 256, 0, stream>>>(ei + NE, deg);
  k_scanA  <<<NB_SCAN, 256, 0, stream>>>(deg, rowptr, bsum);
  k_scanB  <<<1, 512, 0, stream>>>(bsum, boff);
  k_scanC  <<<NB_SCAN, 256, 0, stream>>>(rowptr, boff, cursor);
  k_scatter<<<2048, 256, 0, stream>>>(ei, cursor, csr_src);

  k_gemm1<<<6250, 256, 0, stream>>>(x, W1, asw1, adw1, hub, as1, ad1);
  k_conv1<<<25000, 256, 0, stream>>>(rowptr, csr_src, as1, ad1, hub, b1, hb);
  k_gemm2<<<6250, 256, 0, stream>>>(hb, W2, asw2, adw2, hub, as2, ad2);
  k_conv2<<<25000, 256, 0, stream>>>(rowptr, csr_src, as2, ad2, hub, b2, hb,
                                     lng, lnb, wpool, bpool, es);
  k_sumes<<<128, 256, 0, stream>>>(es, Ssum);
  k_pool <<<391, 256, 0, stream>>>(hb, es, batch, Ssum, pooled);
  k_head <<<64, 64, 0, stream>>>(pooled, wfc1, bfc1, wfc2, bfc2, (float*)d_out);
}

// Round 7
// 404.560 us; speedup vs baseline: 3.3173x; 1.0013x over previous
//
#include <hip/hip_runtime.h>
#include <math.h>

#define NN 100000
#define NE 1600000      // edges WITHOUT self-loops; self-loop handled analytically
#define ICH 128
#define HID 64
#define NGR 64
#define NB_SCAN 391     // ceil(100000/256)

__device__ __forceinline__ float lrelu(float x){ return x > 0.f ? x : 0.2f*x; }
__device__ __forceinline__ float eluf(float x){ return x > 0.f ? x : expm1f(x); }

__device__ __forceinline__ float bf2f(unsigned short u){
  return __uint_as_float(((unsigned int)u) << 16);
}
__device__ __forceinline__ unsigned short f2bf(float f){   // RNE
  unsigned int u = __float_as_uint(f);
  return (unsigned short)((u + 0x7FFF + ((u >> 16) & 1)) >> 16);
}

__device__ __forceinline__ float wsum64(float v){
  #pragma unroll
  for (int m = 32; m >= 1; m >>= 1) v += __shfl_xor(v, m);
  return v;
}
__device__ __forceinline__ float wsum16(float v){
  v += __shfl_xor(v, 8); v += __shfl_xor(v, 4);
  v += __shfl_xor(v, 2); v += __shfl_xor(v, 1);
  return v;
}
__device__ __forceinline__ int wscan_incl(int v){
  const int lane = threadIdx.x & 63;
  #pragma unroll
  for (int d = 1; d < 64; d <<= 1){
    int t = __shfl_up(v, d);
    if (lane >= d) v += t;
  }
  return v;
}

// ---------------- CSR build (XCD/L2-windowed by dst) ----------------
__global__ __launch_bounds__(256) void k_deg(const int* __restrict__ ei_dst,
                                             int* __restrict__ deg)
{
  const int lo = (blockIdx.x & 3) * 25000, hi = lo + 25000;
  const int nb = gridDim.x >> 2, ib = blockIdx.x >> 2;
  for (int e = ib * 256 + threadIdx.x; e < NE; e += nb * 256){
    int d = ei_dst[e];
    if (d >= lo && d < hi) atomicAdd(&deg[d], 1);
  }
}

__global__ __launch_bounds__(256) void k_scanA(const int* __restrict__ deg,
    int* __restrict__ rowptr, int* __restrict__ bsum)
{
  int i = blockIdx.x * 256 + threadIdx.x;
  int v = (i < NN) ? deg[i] : 0;
  int incl = wscan_incl(v);
  __shared__ int wsums[4];
  int w = threadIdx.x >> 6, lane = threadIdx.x & 63;
  if (lane == 63) wsums[w] = incl;
  __syncthreads();
  int off = 0;
  for (int k = 0; k < w; ++k) off += wsums[k];
  if (i < NN) rowptr[i] = incl - v + off;
  if (threadIdx.x == 255) bsum[blockIdx.x] = off + incl;
}

__global__ __launch_bounds__(512) void k_scanB(const int* __restrict__ bsum,
                                               int* __restrict__ boff)
{
  int i = threadIdx.x;
  int v = (i < NB_SCAN) ? bsum[i] : 0;
  int incl = wscan_incl(v);
  __shared__ int wsums[8];
  int w = threadIdx.x >> 6, lane = threadIdx.x & 63;
  if (lane == 63) wsums[w] = incl;
  __syncthreads();
  int off = 0;
  for (int k = 0; k < w; ++k) off += wsums[k];
  if (i < NB_SCAN) boff[i] = incl - v + off;
}

__global__ __launch_bounds__(256) void k_scanC(int* __restrict__ rowptr,
    const int* __restrict__ boff, int* __restrict__ cursor)
{
  int i = blockIdx.x * 256 + threadIdx.x;
  if (i < NN){
    int val = rowptr[i] + boff[blockIdx.x];
    rowptr[i] = val;
    cursor[i] = val;
  }
  if (i == 0) rowptr[NN] = NE;
}

__global__ __launch_bounds__(256) void k_scatter(const int* __restrict__ ei,
    int* __restrict__ cursor, int* __restrict__ csr_src)
{
  const int lo = (blockIdx.x & 7) * 12500, hi = lo + 12500;
  const int nb = gridDim.x >> 3, ib = blockIdx.x >> 3;
  for (int e = ib * 256 + threadIdx.x; e < NE; e += nb * 256){
    int d = ei[NE + e];
    if (d >= lo && d < hi){
      int pos = atomicAdd(&cursor[d], 1);
      csr_src[pos] = ei[e];
    }
  }
}

// ---------------- dense node kernels ----------------
__global__ __launch_bounds__(256) void k_gemm1(const float* __restrict__ x,
    const float* __restrict__ W1, const float* __restrict__ asw,
    const float* __restrict__ adw, unsigned short* __restrict__ h1b,
    float* __restrict__ as1, float* __restrict__ ad1)
{
  __shared__ float xs[16 * ICH];            // 8 KB
  const int t = threadIdx.x;
  const int n0 = blockIdx.x * 16;
  const float4* xg4 = (const float4*)(x + (size_t)n0 * ICH);
  float4* xs4 = (float4*)xs;
  xs4[t]       = xg4[t];
  xs4[t + 256] = xg4[t + 256];
  __syncthreads();

  const int lane = t & 63;
  const float* xr = xs + (t >> 6) * 4 * ICH;   // wave's 4 rows
  float a0 = 0.f, a1 = 0.f, a2 = 0.f, a3 = 0.f;
  #pragma unroll 8
  for (int k = 0; k < ICH; ++k){
    const float w = W1[k * HID + lane];
    a0 = fmaf(xr[k],          w, a0);
    a1 = fmaf(xr[ICH + k],    w, a1);
    a2 = fmaf(xr[2*ICH + k],  w, a2);
    a3 = fmaf(xr[3*ICH + k],  w, a3);
  }
  const float sw = asw[lane], dw = adw[lane];  // att layout [H][16] flattens to [64]
  const int nw = n0 + (t >> 6) * 4;
  float acc[4] = {a0, a1, a2, a3};
  #pragma unroll
  for (int i = 0; i < 4; ++i){
    const int n = nw + i;
    h1b[(size_t)n * HID + lane] = f2bf(acc[i]);
    float ps = wsum16(acc[i] * sw);
    float pd = wsum16(acc[i] * dw);
    if ((lane & 15) == 0){
      as1[n * 4 + (lane >> 4)] = ps;
      ad1[n * 4 + (lane >> 4)] = pd;
    }
  }
}

// conv1: batched edge processing. Lane (h*16+m) computes head h's attention
// exp for edge (base+m) -- ONE expf per lane per 16 edges instead of every
// lane redoing the wave-uniform chain per edge. {e,s} parked in a wave-
// private LDS window; per-edge inner loop = uniform ds_read_b64 + gather+fma.
// Denominator = per-lane partials of own-edge e, one wsum16 at the end.
__global__ __launch_bounds__(256) void k_conv1(const int* __restrict__ rowptr,
    const int* __restrict__ csr_src, const float* __restrict__ as1,
    const float* __restrict__ ad1, const unsigned short* __restrict__ h1b,
    const float* __restrict__ b1, float* __restrict__ hb)
{
  __shared__ float2 buf[256];               // 64 entries per wave
  const int t = threadIdx.x;
  const int lane = t & 63;
  const int h = lane >> 4;                  // head
  const int m = lane & 15;                  // edge slot within batch
  const int woff = t & 192;                 // wave's LDS window base
  const int n = (blockIdx.x * 256 + t) >> 6;
  const int row0 = __builtin_amdgcn_readfirstlane(rowptr[n]);
  const int row1 = __builtin_amdgcn_readfirstlane(rowptr[n + 1]);
  const float adh = ad1[4 * n + h];
  const float eself = __expf(lrelu(as1[4 * n + h] + adh));   // self-loop
  float acc = eself * bf2f(h1b[((unsigned)n << 6) | lane]);
  float den_p = 0.f;
  const int rbase = woff + (lane & 48);
  for (int base = row0; base < row1; base += 16){
    const int cnt = min(16, row1 - base);
    int s = 0; float e = 0.f;
    if (m < cnt){
      s = csr_src[base + m];
      e = __expf(lrelu(as1[4 * s + h] + adh));
    }
    den_p += e;
    buf[woff + lane] = make_float2(e, __int_as_float(s));
    // same-wave RAW: compiler orders via lgkmcnt; buffer is wave-private.
    for (int j = 0; j < cnt; ++j){
      float2 es = buf[rbase + j];           // uniform-addr broadcast read
      int sj = __float_as_int(es.y);
      acc = fmaf(bf2f(h1b[((unsigned)sj << 6) | lane]), es.x, acc);
    }
  }
  float den = wsum16(den_p) + eself;
  float o = acc / (den + 1e-16f) + b1[lane];
  hb[((size_t)n << 6) | lane] = eluf(o);
}

// h2 = h @ W2 (64x64) + scalar-head attention logits; LDS-staged; bf16 out.
__global__ __launch_bounds__(256) void k_gemm2(const float* __restrict__ h,
    const float* __restrict__ W2, const float* __restrict__ asw,
    const float* __restrict__ adw, unsigned short* __restrict__ h2b,
    float* __restrict__ as2, float* __restrict__ ad2)
{
  __shared__ float hs[16 * HID];            // 4 KB
  const int t = threadIdx.x;
  const int n0 = blockIdx.x * 16;
  const float4* hg4 = (const float4*)(h + (size_t)n0 * HID);
  float4* hs4 = (float4*)hs;
  hs4[t] = hg4[t];
  __syncthreads();

  const int lane = t & 63;
  const float* hr = hs + (t >> 6) * 4 * HID;
  float a0 = 0.f, a1 = 0.f, a2 = 0.f, a3 = 0.f;
  #pragma unroll 8
  for (int k = 0; k < HID; ++k){
    const float w = W2[k * HID + lane];
    a0 = fmaf(hr[k],          w, a0);
    a1 = fmaf(hr[HID + k],    w, a1);
    a2 = fmaf(hr[2*HID + k],  w, a2);
    a3 = fmaf(hr[3*HID + k],  w, a3);
  }
  const float sw = asw[lane], dw = adw[lane];
  const int nw = n0 + (t >> 6) * 4;
  float acc[4] = {a0, a1, a2, a3};
  #pragma unroll
  for (int i = 0; i < 4; ++i){
    const int n = nw + i;
    h2b[(size_t)n * HID + lane] = f2bf(acc[i]);
    float ps = wsum64(acc[i] * sw);
    float pd = wsum64(acc[i] * dw);
    if (lane == 0){ as2[n] = ps; ad2[n] = pd; }
  }
}

// conv2: batched edges (64/batch, one expf per lane per batch) + fused
// residual + LayerNorm + elu + pool logit. hf aliases hb (own-row RAW only).
__global__ __launch_bounds__(256) void k_conv2(const int* __restrict__ rowptr,
    const int* __restrict__ csr_src, const float* __restrict__ as2,
    const float* __restrict__ ad2, const unsigned short* __restrict__ h2b,
    const float* __restrict__ b2, float* __restrict__ hb,
    const float* __restrict__ lng, const float* __restrict__ lnb,
    const float* __restrict__ wpool, const float* __restrict__ bpool,
    float* __restrict__ es)
{
  __shared__ float2 buf[256];               // 64 entries per wave
  const int t = threadIdx.x;
  const int lane = t & 63;
  const int woff = t & 192;
  const int n = (blockIdx.x * 256 + t) >> 6;
  const int row0 = __builtin_amdgcn_readfirstlane(rowptr[n]);
  const int row1 = __builtin_amdgcn_readfirstlane(rowptr[n + 1]);
  const float adn = ad2[n];
  const float eself = __expf(lrelu(as2[n] + adn));   // self-loop
  float acc = eself * bf2f(h2b[((unsigned)n << 6) | lane]);
  float den_p = 0.f;
  for (int base = row0; base < row1; base += 64){
    const int cnt = min(64, row1 - base);
    int s = 0; float e = 0.f;
    if (lane < cnt){
      s = csr_src[base + lane];
      e = __expf(lrelu(as2[s] + adn));
    }
    den_p += e;
    buf[woff + lane] = make_float2(e, __int_as_float(s));
    for (int j = 0; j < cnt; ++j){
      float2 esv = buf[woff + j];           // uniform-addr broadcast read
      int sj = __float_as_int(esv.y);
      acc = fmaf(bf2f(h2b[((unsigned)sj << 6) | lane]), esv.x, acc);
    }
  }
  float den = wsum64(den_p) + eself;
  const size_t idxn = ((size_t)n << 6) | lane;
  float tv = acc / (den + 1e-16f) + b2[lane] + hb[idxn];
  float mu  = wsum64(tv) * (1.f / 64.f);
  float dv  = tv - mu;
  float var = wsum64(dv * dv) * (1.f / 64.f);
  float hv = dv * (1.f / sqrtf(var + 1e-5f)) * lng[lane] + lnb[lane];
  hv = eluf(hv);
  hb[idxn] = hv;
  float sl = wsum64(hv * wpool[lane]) + bpool[0];
  if (lane == 0) es[n] = __expf(sl);   // global softmax: max-shift dropped
}

__global__ __launch_bounds__(256) void k_sumes(const float* __restrict__ es,
                                               float* __restrict__ S)
{
  float v = 0.f;
  for (int i = blockIdx.x * 256 + threadIdx.x; i < NN; i += gridDim.x * 256)
    v += es[i];
  v = wsum64(v);
  __shared__ float red[4];
  if ((threadIdx.x & 63) == 0) red[threadIdx.x >> 6] = v;
  __syncthreads();
  if (threadIdx.x == 0) atomicAdd(S, red[0] + red[1] + red[2] + red[3]);
}

__global__ __launch_bounds__(256) void k_pool(const float* __restrict__ hf,
    const float* __restrict__ es, const int* __restrict__ batch,
    const float* __restrict__ S, float* __restrict__ pooled)
{
  const int lane = threadIdx.x & 63;
  const int wseg = blockIdx.x * 4 + (threadIdx.x >> 6);
  const int base = wseg * 64;
  if (base >= NN) return;
  const float invS = 1.f / S[0];
  int end = base + 64; if (end > NN) end = NN;
  float acc = 0.f;
  int gprev = batch[base];
  for (int n = base; n < end; ++n){
    int g = batch[n];
    if (g != gprev){
      atomicAdd(&pooled[gprev * HID + lane], acc);
      acc = 0.f; gprev = g;
    }
    acc = fmaf(hf[(size_t)n * HID + lane], es[n] * invS, acc);
  }
  atomicAdd(&pooled[gprev * HID + lane], acc);
}

__global__ __launch_bounds__(64) void k_head(const float* __restrict__ pooled,
    const float* __restrict__ wfc1, const float* __restrict__ bfc1,
    const float* __restrict__ wfc2, const float* __restrict__ bfc2,
    float* __restrict__ out)
{
  const int g = blockIdx.x, j = threadIdx.x;
  const float* pr = pooled + g * HID;
  float acc = bfc1[j];
  #pragma unroll 4
  for (int k = 0; k < HID; ++k) acc = fmaf(pr[k], wfc1[k * HID + j], acc);
  float z = eluf(acc);
  float r = wsum64(z * wfc2[j]);
  if (j == 0) out[g] = r + bfc2[0];
}

extern "C" void kernel_launch(void* const* d_in, const int* in_sizes, int n_in,
                              void* d_out, int out_size, void* d_ws, size_t ws_size,
                              hipStream_t stream)
{
  const float* x     = (const float*)d_in[0];
  const int*   ei    = (const int*)d_in[1];
  const int*   batch = (const int*)d_in[2];
  const float* W1    = (const float*)d_in[4];
  const float* asw1  = (const float*)d_in[5];
  const float* adw1  = (const float*)d_in[6];
  const float* b1    = (const float*)d_in[7];
  const float* W2    = (const float*)d_in[8];
  const float* asw2  = (const float*)d_in[9];
  const float* adw2  = (const float*)d_in[10];
  const float* b2    = (const float*)d_in[11];
  const float* lng   = (const float*)d_in[12];
  const float* lnb   = (const float*)d_in[13];
  const float* wpool = (const float*)d_in[14];
  const float* bpool = (const float*)d_in[15];
  const float* wfc1  = (const float*)d_in[16];
  const float* bfc1  = (const float*)d_in[17];
  const float* wfc2  = (const float*)d_in[18];
  const float* bfc2  = (const float*)d_in[19];

  float* ws = (float*)d_ws;
  float* hb     = ws;               // NN*64 fp32: conv1 out -> residual -> hf
  float* as1    = ws +  6400000;    // NN*4
  float* ad1    = ws +  6800000;    // NN*4
  float* as2    = ws +  7200000;    // NN
  float* ad2    = ws +  7300000;    // NN
  float* es     = ws +  7400000;    // NN
  float* pooled = ws +  7500000;    // 64*64
  float* Ssum   = ws +  7504096;    // 1
  unsigned short* hub = (unsigned short*)(ws + 7504100);  // NN*64 bf16 (h1b, then h2b)
  int* iw       = (int*)(ws + 10704100);
  int* rowptr   = iw;               // NN+1 (pad 100004)
  int* cursor   = iw + 100004;      // NN
  int* deg      = iw + 200008;      // NN
  int* bsum     = iw + 300008;      // 512
  int* boff     = iw + 300520;      // 512
  int* csr_src  = iw + 301032;      // NE
  // total ~12.6M words = 50.4 MB of d_ws

  hipMemsetAsync(deg, 0, (size_t)NN * 4, stream);
  hipMemsetAsync(pooled, 0, (size_t)NGR * 64 * 4, stream);
  hipMemsetAsync(Ssum, 0, 4, stream);

  // CSR build (self-loops excluded; handled analytically in conv)
  k_deg    <<<2048, 256, 0, stream>>>(ei + NE, deg);
  k_scanA  <<<NB_SCAN, 256, 0, stream>>>(deg, rowptr, bsum);
  k_scanB  <<<1, 512, 0, stream>>>(bsum, boff);
  k_scanC  <<<NB_SCAN, 256, 0, stream>>>(rowptr, boff, cursor);
  k_scatter<<<2048, 256, 0, stream>>>(ei, cursor, csr_src);

  k_gemm1<<<6250, 256, 0, stream>>>(x, W1, asw1, adw1, hub, as1, ad1);
  k_conv1<<<25000, 256, 0, stream>>>(rowptr, csr_src, as1, ad1, hub, b1, hb);
  k_gemm2<<<6250, 256, 0, stream>>>(hb, W2, asw2, adw2, hub, as2, ad2);
  k_conv2<<<25000, 256, 0, stream>>>(rowptr, csr_src, as2, ad2, hub, b2, hb,
                                     lng, lnb, wpool, bpool, es);
  k_sumes<<<128, 256, 0, stream>>>(es, Ssum);
  k_pool <<<391, 256, 0, stream>>>(hb, es, batch, Ssum, pooled);
  k_head <<<64, 64, 0, stream>>>(pooled, wfc1, bfc1, wfc2, bfc2, (float*)d_out);
}

// Round 8
// 403.161 us; speedup vs baseline: 3.3288x; 1.0035x over previous
//
#include <hip/hip_runtime.h>
#include <math.h>

#define NN 100000
#define NE 1600000      // edges WITHOUT self-loops; self-loop handled analytically
#define ICH 128
#define HID 64
#define NGR 64
#define NB_SCAN 391     // ceil(100000/256)

__device__ __forceinline__ float lrelu(float x){ return x > 0.f ? x : 0.2f*x; }
__device__ __forceinline__ float eluf(float x){ return x > 0.f ? x : expm1f(x); }

__device__ __forceinline__ float bf2f(unsigned short u){
  return __uint_as_float(((unsigned int)u) << 16);
}
__device__ __forceinline__ unsigned short f2bf(float f){   // RNE
  unsigned int u = __float_as_uint(f);
  return (unsigned short)((u + 0x7FFF + ((u >> 16) & 1)) >> 16);
}

__device__ __forceinline__ float wsum64(float v){
  #pragma unroll
  for (int m = 32; m >= 1; m >>= 1) v += __shfl_xor(v, m);
  return v;
}
__device__ __forceinline__ float wsum16(float v){
  v += __shfl_xor(v, 8); v += __shfl_xor(v, 4);
  v += __shfl_xor(v, 2); v += __shfl_xor(v, 1);
  return v;
}
__device__ __forceinline__ int wscan_incl(int v){
  const int lane = threadIdx.x & 63;
  #pragma unroll
  for (int d = 1; d < 64; d <<= 1){
    int t = __shfl_up(v, d);
    if (lane >= d) v += t;
  }
  return v;
}

// ---------------- CSR build (XCD/L2-windowed by dst) ----------------
__global__ __launch_bounds__(256) void k_deg(const int* __restrict__ ei_dst,
                                             int* __restrict__ deg)
{
  const int lo = (blockIdx.x & 3) * 25000, hi = lo + 25000;
  const int nb = gridDim.x >> 2, ib = blockIdx.x >> 2;
  for (int e = ib * 256 + threadIdx.x; e < NE; e += nb * 256){
    int d = ei_dst[e];
    if (d >= lo && d < hi) atomicAdd(&deg[d], 1);
  }
}

__global__ __launch_bounds__(256) void k_scanA(const int* __restrict__ deg,
    int* __restrict__ rowptr, int* __restrict__ bsum)
{
  int i = blockIdx.x * 256 + threadIdx.x;
  int v = (i < NN) ? deg[i] : 0;
  int incl = wscan_incl(v);
  __shared__ int wsums[4];
  int w = threadIdx.x >> 6, lane = threadIdx.x & 63;
  if (lane == 63) wsums[w] = incl;
  __syncthreads();
  int off = 0;
  for (int k = 0; k < w; ++k) off += wsums[k];
  if (i < NN) rowptr[i] = incl - v + off;
  if (threadIdx.x == 255) bsum[blockIdx.x] = off + incl;
}

__global__ __launch_bounds__(512) void k_scanB(const int* __restrict__ bsum,
                                               int* __restrict__ boff)
{
  int i = threadIdx.x;
  int v = (i < NB_SCAN) ? bsum[i] : 0;
  int incl = wscan_incl(v);
  __shared__ int wsums[8];
  int w = threadIdx.x >> 6, lane = threadIdx.x & 63;
  if (lane == 63) wsums[w] = incl;
  __syncthreads();
  int off = 0;
  for (int k = 0; k < w; ++k) off += wsums[k];
  if (i < NB_SCAN) boff[i] = incl - v + off;
}

__global__ __launch_bounds__(256) void k_scanC(int* __restrict__ rowptr,
    const int* __restrict__ boff, int* __restrict__ cursor)
{
  int i = blockIdx.x * 256 + threadIdx.x;
  if (i < NN){
    int val = rowptr[i] + boff[blockIdx.x];
    rowptr[i] = val;
    cursor[i] = val;
  }
  if (i == 0) rowptr[NN] = NE;
}

__global__ __launch_bounds__(256) void k_scatter(const int* __restrict__ ei,
    int* __restrict__ cursor, int* __restrict__ csr_src)
{
  const int lo = (blockIdx.x & 7) * 12500, hi = lo + 12500;
  const int nb = gridDim.x >> 3, ib = blockIdx.x >> 3;
  for (int e = ib * 256 + threadIdx.x; e < NE; e += nb * 256){
    int d = ei[NE + e];
    if (d >= lo && d < hi){
      int pos = atomicAdd(&cursor[d], 1);
      csr_src[pos] = ei[e];
    }
  }
}

// ---------------- dense node kernels ----------------
__global__ __launch_bounds__(256) void k_gemm1(const float* __restrict__ x,
    const float* __restrict__ W1, const float* __restrict__ asw,
    const float* __restrict__ adw, unsigned short* __restrict__ h1b,
    float* __restrict__ as1, float* __restrict__ ad1)
{
  __shared__ float xs[16 * ICH];            // 8 KB
  const int t = threadIdx.x;
  const int n0 = blockIdx.x * 16;
  const float4* xg4 = (const float4*)(x + (size_t)n0 * ICH);
  float4* xs4 = (float4*)xs;
  xs4[t]       = xg4[t];
  xs4[t + 256] = xg4[t + 256];
  __syncthreads();

  const int lane = t & 63;
  const float* xr = xs + (t >> 6) * 4 * ICH;   // wave's 4 rows
  float a0 = 0.f, a1 = 0.f, a2 = 0.f, a3 = 0.f;
  #pragma unroll 8
  for (int k = 0; k < ICH; ++k){
    const float w = W1[k * HID + lane];
    a0 = fmaf(xr[k],          w, a0);
    a1 = fmaf(xr[ICH + k],    w, a1);
    a2 = fmaf(xr[2*ICH + k],  w, a2);
    a3 = fmaf(xr[3*ICH + k],  w, a3);
  }
  const float sw = asw[lane], dw = adw[lane];  // att layout [H][16] flattens to [64]
  const int nw = n0 + (t >> 6) * 4;
  float acc[4] = {a0, a1, a2, a3};
  #pragma unroll
  for (int i = 0; i < 4; ++i){
    const int n = nw + i;
    h1b[(size_t)n * HID + lane] = f2bf(acc[i]);
    float ps = wsum16(acc[i] * sw);
    float pd = wsum16(acc[i] * dw);
    if ((lane & 15) == 0){
      as1[n * 4 + (lane >> 4)] = ps;
      ad1[n * 4 + (lane >> 4)] = pd;
    }
  }
}

// conv1: batched edges (16/batch, lane h*16+m computes head h of edge m) with
// 4x-unrolled broadcast loop: 4 ds_reads + 4 independent gathers in flight +
// 4 accumulators -> breaks the per-edge dependent-latency chain.
__global__ __launch_bounds__(256) void k_conv1(const int* __restrict__ rowptr,
    const int* __restrict__ csr_src, const float* __restrict__ as1,
    const float* __restrict__ ad1, const unsigned short* __restrict__ h1b,
    const float* __restrict__ b1, float* __restrict__ hb)
{
  __shared__ float2 buf[256];               // 64 entries per wave
  const int t = threadIdx.x;
  const int lane = t & 63;
  const int h = lane >> 4;                  // head
  const int m = lane & 15;                  // edge slot within batch
  const int woff = t & 192;                 // wave's LDS window base
  const int n = (blockIdx.x * 256 + t) >> 6;
  const int row0 = __builtin_amdgcn_readfirstlane(rowptr[n]);
  const int row1 = __builtin_amdgcn_readfirstlane(rowptr[n + 1]);
  const float adh = ad1[4 * n + h];
  const float eself = __expf(lrelu(as1[4 * n + h] + adh));   // self-loop
  const unsigned short* __restrict__ hrow = h1b + lane;
  float a0 = eself * bf2f(hrow[(unsigned)n << 6]);
  float a1 = 0.f, a2 = 0.f, a3 = 0.f;
  float den_p = 0.f;
  const int rbase = woff + (lane & 48);     // = woff + h*16
  for (int base = row0; base < row1; base += 16){
    const int cnt = min(16, row1 - base);
    int s = 0; float e = 0.f;
    if (m < cnt){
      s = csr_src[base + m];
      e = __expf(lrelu(as1[4 * s + h] + adh));
    }
    den_p += e;
    buf[woff + lane] = make_float2(e, __int_as_float(s));
    // same-wave RAW: compiler orders via lgkmcnt; buffer is wave-private.
    int j = 0;
    for (; j + 4 <= cnt; j += 4){
      float2 p0 = buf[rbase + j];
      float2 p1 = buf[rbase + j + 1];
      float2 p2 = buf[rbase + j + 2];
      float2 p3 = buf[rbase + j + 3];
      float v0 = bf2f(hrow[(unsigned)__float_as_int(p0.y) << 6]);
      float v1 = bf2f(hrow[(unsigned)__float_as_int(p1.y) << 6]);
      float v2 = bf2f(hrow[(unsigned)__float_as_int(p2.y) << 6]);
      float v3 = bf2f(hrow[(unsigned)__float_as_int(p3.y) << 6]);
      a0 = fmaf(v0, p0.x, a0);
      a1 = fmaf(v1, p1.x, a1);
      a2 = fmaf(v2, p2.x, a2);
      a3 = fmaf(v3, p3.x, a3);
    }
    for (; j < cnt; ++j){
      float2 p0 = buf[rbase + j];
      a0 = fmaf(bf2f(hrow[(unsigned)__float_as_int(p0.y) << 6]), p0.x, a0);
    }
  }
  float acc = (a0 + a1) + (a2 + a3);
  float den = wsum16(den_p) + eself;
  float o = acc / (den + 1e-16f) + b1[lane];
  hb[((size_t)n << 6) | lane] = eluf(o);
}

// h2 = h @ W2 (64x64) + scalar-head attention logits; LDS-staged; bf16 out.
__global__ __launch_bounds__(256) void k_gemm2(const float* __restrict__ h,
    const float* __restrict__ W2, const float* __restrict__ asw,
    const float* __restrict__ adw, unsigned short* __restrict__ h2b,
    float* __restrict__ as2, float* __restrict__ ad2)
{
  __shared__ float hs[16 * HID];            // 4 KB
  const int t = threadIdx.x;
  const int n0 = blockIdx.x * 16;
  const float4* hg4 = (const float4*)(h + (size_t)n0 * HID);
  float4* hs4 = (float4*)hs;
  hs4[t] = hg4[t];
  __syncthreads();

  const int lane = t & 63;
  const float* hr = hs + (t >> 6) * 4 * HID;
  float a0 = 0.f, a1 = 0.f, a2 = 0.f, a3 = 0.f;
  #pragma unroll 8
  for (int k = 0; k < HID; ++k){
    const float w = W2[k * HID + lane];
    a0 = fmaf(hr[k],          w, a0);
    a1 = fmaf(hr[HID + k],    w, a1);
    a2 = fmaf(hr[2*HID + k],  w, a2);
    a3 = fmaf(hr[3*HID + k],  w, a3);
  }
  const float sw = asw[lane], dw = adw[lane];
  const int nw = n0 + (t >> 6) * 4;
  float acc[4] = {a0, a1, a2, a3};
  #pragma unroll
  for (int i = 0; i < 4; ++i){
    const int n = nw + i;
    h2b[(size_t)n * HID + lane] = f2bf(acc[i]);
    float ps = wsum64(acc[i] * sw);
    float pd = wsum64(acc[i] * dw);
    if (lane == 0){ as2[n] = ps; ad2[n] = pd; }
  }
}

// conv2: batched edges (64/batch) with 4x-unrolled broadcast loop + fused
// residual + LayerNorm + elu + pool logit. hf aliases hb (own-row RAW only).
__global__ __launch_bounds__(256) void k_conv2(const int* __restrict__ rowptr,
    const int* __restrict__ csr_src, const float* __restrict__ as2,
    const float* __restrict__ ad2, const unsigned short* __restrict__ h2b,
    const float* __restrict__ b2, float* __restrict__ hb,
    const float* __restrict__ lng, const float* __restrict__ lnb,
    const float* __restrict__ wpool, const float* __restrict__ bpool,
    float* __restrict__ es)
{
  __shared__ float2 buf[256];               // 64 entries per wave
  const int t = threadIdx.x;
  const int lane = t & 63;
  const int woff = t & 192;
  const int n = (blockIdx.x * 256 + t) >> 6;
  const int row0 = __builtin_amdgcn_readfirstlane(rowptr[n]);
  const int row1 = __builtin_amdgcn_readfirstlane(rowptr[n + 1]);
  const float adn = ad2[n];
  const float eself = __expf(lrelu(as2[n] + adn));   // self-loop
  const unsigned short* __restrict__ hrow = h2b + lane;
  float a0 = eself * bf2f(hrow[(unsigned)n << 6]);
  float a1 = 0.f, a2 = 0.f, a3 = 0.f;
  float den_p = 0.f;
  for (int base = row0; base < row1; base += 64){
    const int cnt = min(64, row1 - base);
    int s = 0; float e = 0.f;
    if (lane < cnt){
      s = csr_src[base + lane];
      e = __expf(lrelu(as2[s] + adn));
    }
    den_p += e;
    buf[woff + lane] = make_float2(e, __int_as_float(s));
    int j = 0;
    for (; j + 4 <= cnt; j += 4){
      float2 p0 = buf[woff + j];
      float2 p1 = buf[woff + j + 1];
      float2 p2 = buf[woff + j + 2];
      float2 p3 = buf[woff + j + 3];
      float v0 = bf2f(hrow[(unsigned)__float_as_int(p0.y) << 6]);
      float v1 = bf2f(hrow[(unsigned)__float_as_int(p1.y) << 6]);
      float v2 = bf2f(hrow[(unsigned)__float_as_int(p2.y) << 6]);
      float v3 = bf2f(hrow[(unsigned)__float_as_int(p3.y) << 6]);
      a0 = fmaf(v0, p0.x, a0);
      a1 = fmaf(v1, p1.x, a1);
      a2 = fmaf(v2, p2.x, a2);
      a3 = fmaf(v3, p3.x, a3);
    }
    for (; j < cnt; ++j){
      float2 p0 = buf[woff + j];
      a0 = fmaf(bf2f(hrow[(unsigned)__float_as_int(p0.y) << 6]), p0.x, a0);
    }
  }
  float acc = (a0 + a1) + (a2 + a3);
  float den = wsum64(den_p) + eself;
  const size_t idxn = ((size_t)n << 6) | lane;
  float tv = acc / (den + 1e-16f) + b2[lane] + hb[idxn];
  float mu  = wsum64(tv) * (1.f / 64.f);
  float dv  = tv - mu;
  float var = wsum64(dv * dv) * (1.f / 64.f);
  float hv = dv * (1.f / sqrtf(var + 1e-5f)) * lng[lane] + lnb[lane];
  hv = eluf(hv);
  hb[idxn] = hv;
  float sl = wsum64(hv * wpool[lane]) + bpool[0];
  if (lane == 0) es[n] = __expf(sl);   // global softmax: max-shift dropped
}

__global__ __launch_bounds__(256) void k_sumes(const float* __restrict__ es,
                                               float* __restrict__ S)
{
  float v = 0.f;
  for (int i = blockIdx.x * 256 + threadIdx.x; i < NN; i += gridDim.x * 256)
    v += es[i];
  v = wsum64(v);
  __shared__ float red[4];
  if ((threadIdx.x & 63) == 0) red[threadIdx.x >> 6] = v;
  __syncthreads();
  if (threadIdx.x == 0) atomicAdd(S, red[0] + red[1] + red[2] + red[3]);
}

__global__ __launch_bounds__(256) void k_pool(const float* __restrict__ hf,
    const float* __restrict__ es, const int* __restrict__ batch,
    const float* __restrict__ S, float* __restrict__ pooled)
{
  const int lane = threadIdx.x & 63;
  const int wseg = blockIdx.x * 4 + (threadIdx.x >> 6);
  const int base = wseg * 64;
  if (base >= NN) return;
  const float invS = 1.f / S[0];
  int end = base + 64; if (end > NN) end = NN;
  float acc = 0.f;
  int gprev = batch[base];
  for (int n = base; n < end; ++n){
    int g = batch[n];
    if (g != gprev){
      atomicAdd(&pooled[gprev * HID + lane], acc);
      acc = 0.f; gprev = g;
    }
    acc = fmaf(hf[(size_t)n * HID + lane], es[n] * invS, acc);
  }
  atomicAdd(&pooled[gprev * HID + lane], acc);
}

__global__ __launch_bounds__(64) void k_head(const float* __restrict__ pooled,
    const float* __restrict__ wfc1, const float* __restrict__ bfc1,
    const float* __restrict__ wfc2, const float* __restrict__ bfc2,
    float* __restrict__ out)
{
  const int g = blockIdx.x, j = threadIdx.x;
  const float* pr = pooled + g * HID;
  float acc = bfc1[j];
  #pragma unroll 4
  for (int k = 0; k < HID; ++k) acc = fmaf(pr[k], wfc1[k * HID + j], acc);
  float z = eluf(acc);
  float r = wsum64(z * wfc2[j]);
  if (j == 0) out[g] = r + bfc2[0];
}

extern "C" void kernel_launch(void* const* d_in, const int* in_sizes, int n_in,
                              void* d_out, int out_size, void* d_ws, size_t ws_size,
                              hipStream_t stream)
{
  const float* x     = (const float*)d_in[0];
  const int*   ei    = (const int*)d_in[1];
  const int*   batch = (const int*)d_in[2];
  const float* W1    = (const float*)d_in[4];
  const float* asw1  = (const float*)d_in[5];
  const float* adw1  = (const float*)d_in[6];
  const float* b1    = (const float*)d_in[7];
  const float* W2    = (const float*)d_in[8];
  const float* asw2  = (const float*)d_in[9];
  const float* adw2  = (const float*)d_in[10];
  const float* b2    = (const float*)d_in[11];
  const float* lng   = (const float*)d_in[12];
  const float* lnb   = (const float*)d_in[13];
  const float* wpool = (const float*)d_in[14];
  const float* bpool = (const float*)d_in[15];
  const float* wfc1  = (const float*)d_in[16];
  const float* bfc1  = (const float*)d_in[17];
  const float* wfc2  = (const float*)d_in[18];
  const float* bfc2  = (const float*)d_in[19];

  float* ws = (float*)d_ws;
  float* hb     = ws;               // NN*64 fp32: conv1 out -> residual -> hf
  float* as1    = ws +  6400000;    // NN*4
  float* ad1    = ws +  6800000;    // NN*4
  float* as2    = ws +  7200000;    // NN
  float* ad2    = ws +  7300000;    // NN
  float* es     = ws +  7400000;    // NN
  float* pooled = ws +  7500000;    // 64*64
  float* Ssum   = ws +  7504096;    // 1
  unsigned short* hub = (unsigned short*)(ws + 7504100);  // NN*64 bf16 (h1b, then h2b)
  int* iw       = (int*)(ws + 10704100);
  int* rowptr   = iw;               // NN+1 (pad 100004)
  int* cursor   = iw + 100004;      // NN
  int* deg      = iw + 200008;      // NN
  int* bsum     = iw + 300008;      // 512
  int* boff     = iw + 300520;      // 512
  int* csr_src  = iw + 301032;      // NE
  // total ~12.6M words = 50.4 MB of d_ws

  hipMemsetAsync(deg, 0, (size_t)NN * 4, stream);
  hipMemsetAsync(pooled, 0, (size_t)NGR * 64 * 4, stream);
  hipMemsetAsync(Ssum, 0, 4, stream);

  // CSR build (self-loops excluded; handled analytically in conv)
  k_deg    <<<2048, 256, 0, stream>>>(ei + NE, deg);
  k_scanA  <<<NB_SCAN, 256, 0, stream>>>(deg, rowptr, bsum);
  k_scanB  <<<1, 512, 0, stream>>>(bsum, boff);
  k_scanC  <<<NB_SCAN, 256, 0, stream>>>(rowptr, boff, cursor);
  k_scatter<<<2048, 256, 0, stream>>>(ei, cursor, csr_src);

  k_gemm1<<<6250, 256, 0, stream>>>(x, W1, asw1, adw1, hub, as1, ad1);
  k_conv1<<<25000, 256, 0, stream>>>(rowptr, csr_src, as1, ad1, hub, b1, hb);
  k_gemm2<<<6250, 256, 0, stream>>>(hb, W2, asw2, adw2, hub, as2, ad2);
  k_conv2<<<25000, 256, 0, stream>>>(rowptr, csr_src, as2, ad2, hub, b2, hb,
                                     lng, lnb, wpool, bpool, es);
  k_sumes<<<128, 256, 0, stream>>>(es, Ssum);
  k_pool <<<391, 256, 0, stream>>>(hb, es, batch, Ssum, pooled);
  k_head <<<64, 64, 0, stream>>>(pooled, wfc1, bfc1, wfc2, bfc2, (float*)d_out);
}